// Round 1
// baseline (2688.160 us; speedup 1.0000x reference)
//
#include <hip/hip_runtime.h>
#include <hip/hip_cooperative_groups.h>
#include <math.h>

namespace cg = cooperative_groups;

#define Bb 128
#define Tt 25
#define Vv 10000
#define Ee 512
#define Aa 512
#define Hh 512
#define ENCc 2048
#define Pp 196
#define NSTEP 24
#define NPAD 10112  // 79*128
#define NWG 128     // cooperative loop workgroups (1 per CU-half, N-strip 16)

#define OUT_CAPS  ((size_t)Bb*Tt*Vv)            // 32,000,000
#define OUT_LENS  (OUT_CAPS + (size_t)Bb*Tt)    // 32,003,200
#define OUT_SORT  (OUT_LENS + Bb)               // 32,003,328

typedef __bf16 bf16x8 __attribute__((ext_vector_type(8)));
typedef __bf16 bf16x4 __attribute__((ext_vector_type(4)));
typedef float  f32x4  __attribute__((ext_vector_type(4)));

__device__ __forceinline__ float sigm(float x) { return 1.0f / (1.0f + expf(-x)); }

// ---------------- sort + index maps + int outputs ----------------
__global__ void k_sort(const int* __restrict__ captions, const int* __restrict__ cap_lens,
                       int* sort_ind, int* lens_s, int* caps_s,
                       int* row_emb, int* logit_rowoff, int* logit_mask,
                       float* out)
{
    int b = threadIdx.x; // 0..127
    __shared__ int lens_sh[Bb];
    int len = cap_lens[b];
    lens_sh[b] = len;
    __syncthreads();
    int r = 0;
    for (int k = 0; k < Bb; k++) {
        int lk = lens_sh[k];
        if (lk > len || (lk == len && k < b)) r++;
    }
    sort_ind[r] = b;
    lens_s[r] = len;
    for (int t = 0; t < Tt; t++) {
        int cv = captions[b * Tt + t];
        caps_s[r * Tt + t] = cv;
        out[OUT_CAPS + (size_t)r * Tt + t] = (float)cv;
    }
    out[OUT_LENS + r] = (float)len;
    out[OUT_SORT + r] = (float)b;
    __syncthreads();
    for (int m = b; m < NSTEP * Bb; m += Bb) {
        int t = m / Bb, bb = m % Bb;
        row_emb[m] = caps_s[bb * Tt + t];
        logit_rowoff[m] = (bb * Tt + (t + 1)) * Vv;
        logit_mask[m] = (lens_s[bb] > t + 1) ? 1 : 0;
    }
}

__global__ void k_preds0(float* out)
{
    size_t i = (size_t)blockIdx.x * 256 + threadIdx.x;
    if (i >= (size_t)Bb * Vv) return;
    size_t b = i / Vv, v = i % Vv;
    out[b * Tt * Vv + v] = (v == 0) ? 1.0f : 0.0f;
}

// bias2 = b_ih + b_hh ; bias_att = att_enc_b + att_dec_b
__global__ void k_bias(const float* b_ih, const float* b_hh,
                       const float* aeb, const float* adb,
                       float* bias2, float* bias_att)
{
    int i = blockIdx.x * 256 + threadIdx.x;
    if (i < 2048) bias2[i] = b_ih[i] + b_hh[i];
    if (i < 512)  bias_att[i] = aeb[i] + adb[i];
}

// ---------------- conversions ----------------
__global__ void k_cvt_enc(const float* __restrict__ src, const int* __restrict__ sind,
                          __bf16* __restrict__ dst)
{
    int row = blockIdx.y;                       // sorted row
    int e4 = blockIdx.x * 256 + threadIdx.x;
    int b = row / Pp, p = row % Pp;
    const float4 v = *(const float4*)(src + ((size_t)(sind[b] * Pp + p)) * ENCc + e4 * 4);
    bf16x4 o = { (__bf16)v.x, (__bf16)v.y, (__bf16)v.z, (__bf16)v.w };
    *(bf16x4*)(dst + (size_t)row * ENCc + e4 * 4) = o;
}

__global__ void k_cvt(const float* __restrict__ src, __bf16* __restrict__ dst, int n4)
{
    int i = blockIdx.x * 256 + threadIdx.x;
    if (i >= n4) return;
    const float4 v = *(const float4*)(src + (size_t)i * 4);
    bf16x4 o = { (__bf16)v.x, (__bf16)v.y, (__bf16)v.z, (__bf16)v.w };
    *(bf16x4*)(dst + (size_t)i * 4) = o;
}

__global__ void k_cvt_lin(const float* __restrict__ src, __bf16* __restrict__ dst)
{
    int i = blockIdx.x * 256 + threadIdx.x;     // over NPAD*128
    if (i >= NPAD * 128) return;
    int row = i >> 7, e = (i & 127) * 4;
    bf16x4 o;
    if (row < Vv) {
        const float4 v = *(const float4*)(src + (size_t)row * Hh + e);
        o = bf16x4{ (__bf16)v.x, (__bf16)v.y, (__bf16)v.z, (__bf16)v.w };
    } else {
        o = bf16x4{ (__bf16)0.f, (__bf16)0.f, (__bf16)0.f, (__bf16)0.f };
    }
    *(bf16x4*)(dst + (size_t)row * Hh + e) = o;
}

__global__ void k_cvt_emb(const float* __restrict__ emb_W, const int* __restrict__ row_emb,
                          __bf16* __restrict__ dst)
{
    int i = blockIdx.x * 256 + threadIdx.x;     // over 3072*128
    int row = i >> 7, e = (i & 127) * 4;
    const float4 v = *(const float4*)(emb_W + (size_t)row_emb[row] * Ee + e);
    bf16x4 o = { (__bf16)v.x, (__bf16)v.y, (__bf16)v.z, (__bf16)v.w };
    *(bf16x4*)(dst + (size_t)row * Ee + e) = o;
}

// Wihd (2048x512 bf16) = W_ih[:, 2048:2560]
__global__ void k_cvt_wihd(const float* __restrict__ W_ih, __bf16* __restrict__ dst)
{
    int i = blockIdx.x * 256 + threadIdx.x;     // over 2048*128
    int row = i >> 7, e = (i & 127) * 4;
    const float4 v = *(const float4*)(W_ih + (size_t)row * 2560 + 2048 + e);
    bf16x4 o = { (__bf16)v.x, (__bf16)v.y, (__bf16)v.z, (__bf16)v.w };
    *(bf16x4*)(dst + (size_t)row * 512 + e) = o;
}

// W2 (2048x2560 bf16) = [W_ih[:, :2048] | W_hh]
__global__ void k_wcat2(const float* __restrict__ W_ih, const float* __restrict__ W_hh,
                        __bf16* __restrict__ W2)
{
    int n = blockIdx.y;
    int k4 = blockIdx.x * 256 + threadIdx.x;    // 0..639
    if (k4 >= 640) return;
    int k = k4 * 4;
    float4 v;
    if (k < 2048) v = *(const float4*)(W_ih + (size_t)n * 2560 + k);
    else          v = *(const float4*)(W_hh + (size_t)n * 512 + (k - 2048));
    bf16x4 o = { (__bf16)v.x, (__bf16)v.y, (__bf16)v.z, (__bf16)v.w };
    *(bf16x4*)(W2 + (size_t)n * 2560 + k) = o;
}

// ---------------- enc mean (bf16 in, bf16 out) ----------------
__global__ void k_enc_mean(const __bf16* __restrict__ enc, __bf16* __restrict__ emean)
{
    int b = blockIdx.y;
    int e = blockIdx.x * 256 + threadIdx.x;
    const __bf16* base = enc + (size_t)b * Pp * ENCc + e;
    float s = 0.0f;
    for (int p = 0; p < Pp; p++) s += (float)base[(size_t)p * ENCc];
    emean[(size_t)b * ENCc + e] = (__bf16)(s / 196.0f);
}

// ---------------- MFMA GEMM: C = A @ B^T (+bias), 128x128 tile, BK=32 ----------------
// MODE 0: f32 out row-major (stride Nout); MODE 1: bf16 out (stride Nout, col<Ncol)
// MODE 2: f32 out, row scatter (c_rowoff) + mask, col<Ncol
// batched via blockIdx.z with element strides bsA/bsB/bsC
template<int MODE>
__launch_bounds__(256)
__global__ void mfma_gemm(const __bf16* __restrict__ A, const __bf16* __restrict__ B,
                          const float* __restrict__ bias, void* __restrict__ Cout,
                          int K, int Nout, int Ncol,
                          const int* __restrict__ c_rowoff,
                          const int* __restrict__ mmask,
                          size_t bsA, size_t bsB, size_t bsC)
{
    __shared__ __bf16 sA[128 * 32];
    __shared__ __bf16 sB[128 * 32];
    const int tid = threadIdx.x;
    const int lane = tid & 63;
    const int wave = tid >> 6;
    const int z = blockIdx.z;
    const int m0 = blockIdx.y * 128, n0 = blockIdx.x * 128;
    const int wr = (wave & 1) * 64, wc = (wave >> 1) * 64;
    f32x4 acc[4][4] = {};
    const __bf16* Aptr = A + bsA * z + (size_t)m0 * K;
    const __bf16* Bptr = B + bsB * z + (size_t)n0 * K;
    const int c0 = tid, c1 = tid + 256;
    const int ar0 = c0 >> 2, ak0 = (c0 & 3) * 8;
    const int ar1 = c1 >> 2, ak1 = (c1 & 3) * 8;
    const int kq = (lane >> 4) * 8, mr = lane & 15;

    for (int k0 = 0; k0 < K; k0 += 32) {
        __builtin_amdgcn_global_load_lds(
            (const __attribute__((address_space(1))) void*)(Aptr + (size_t)ar0 * K + k0 + ak0),
            (__attribute__((address_space(3))) void*)(sA + c0 * 8), 16, 0, 0);
        __builtin_amdgcn_global_load_lds(
            (const __attribute__((address_space(1))) void*)(Aptr + (size_t)ar1 * K + k0 + ak1),
            (__attribute__((address_space(3))) void*)(sA + c1 * 8), 16, 0, 0);
        __builtin_amdgcn_global_load_lds(
            (const __attribute__((address_space(1))) void*)(Bptr + (size_t)ar0 * K + k0 + ak0),
            (__attribute__((address_space(3))) void*)(sB + c0 * 8), 16, 0, 0);
        __builtin_amdgcn_global_load_lds(
            (const __attribute__((address_space(1))) void*)(Bptr + (size_t)ar1 * K + k0 + ak1),
            (__attribute__((address_space(3))) void*)(sB + c1 * 8), 16, 0, 0);
        __syncthreads();
        bf16x8 af[4], bfr[4];
        #pragma unroll
        for (int i = 0; i < 4; i++)
            af[i] = *(const bf16x8*)(sA + (wr + i * 16 + mr) * 32 + kq);
        #pragma unroll
        for (int j = 0; j < 4; j++)
            bfr[j] = *(const bf16x8*)(sB + (wc + j * 16 + mr) * 32 + kq);
        #pragma unroll
        for (int i = 0; i < 4; i++)
            #pragma unroll
            for (int j = 0; j < 4; j++)
                acc[i][j] = __builtin_amdgcn_mfma_f32_16x16x32_bf16(af[i], bfr[j], acc[i][j], 0, 0, 0);
        __syncthreads();
    }

    const int rq = (lane >> 4) * 4, cq = lane & 15;
    #pragma unroll
    for (int i = 0; i < 4; i++) {
        #pragma unroll
        for (int j = 0; j < 4; j++) {
            #pragma unroll
            for (int r = 0; r < 4; r++) {
                int row = m0 + wr + i * 16 + rq + r;
                int col = n0 + wc + j * 16 + cq;
                if ((MODE == 1 || MODE == 2) && col >= Ncol) continue;
                float v = acc[i][j][r] + (bias ? bias[col] : 0.0f);
                size_t ro = (c_rowoff ? (size_t)c_rowoff[row] : (size_t)row * Nout) + bsC * z;
                if (MODE == 2) {
                    if (!mmask[row]) v = 0.0f;
                    ((float*)Cout)[ro + col] = v;
                } else if (MODE == 1) {
                    ((__bf16*)Cout)[ro + col] = (__bf16)v;
                } else {
                    ((float*)Cout)[ro + col] = v;
                }
            }
        }
    }
}

// ---------------- scores v3: reduction-free, lane<->p ----------------
// ET[b][a][196] bf16 (attenc^T, no bias), D = att_d[t*128+b][512] f32 (both biases folded)
__global__ void k_scores(const __bf16* __restrict__ ET, const float* __restrict__ att_d,
                         const float* __restrict__ fin_W, const float* __restrict__ fin_b,
                         float* __restrict__ wts)
{
    __shared__ float Dls[512 * 12];
    const int b = blockIdx.y;
    const int tb = blockIdx.x * 12;
    const int tid = threadIdx.x;
    #pragma unroll
    for (int tt = 0; tt < 12; tt++)
        for (int a = tid; a < 512; a += 256)
            Dls[a * 12 + tt] = att_d[((size_t)(tb + tt) * Bb + b) * Aa + a];
    __syncthreads();
    const int p = tid;
    if (p >= Pp) return;
    float acc[12];
    #pragma unroll
    for (int i = 0; i < 12; i++) acc[i] = 0.0f;
    const __bf16* ep = ET + (size_t)b * Aa * Pp + p;
    for (int a = 0; a < 512; a++) {
        float e = (float)ep[(size_t)a * Pp];
        float fw = fin_W[a];
        const float4* dp = (const float4*)(Dls + a * 12);
        float4 d0 = dp[0], d1 = dp[1], d2 = dp[2];
        acc[0] += fmaxf(e + d0.x, 0.0f) * fw;
        acc[1] += fmaxf(e + d0.y, 0.0f) * fw;
        acc[2] += fmaxf(e + d0.z, 0.0f) * fw;
        acc[3] += fmaxf(e + d0.w, 0.0f) * fw;
        acc[4] += fmaxf(e + d1.x, 0.0f) * fw;
        acc[5] += fmaxf(e + d1.y, 0.0f) * fw;
        acc[6] += fmaxf(e + d1.z, 0.0f) * fw;
        acc[7] += fmaxf(e + d1.w, 0.0f) * fw;
        acc[8] += fmaxf(e + d2.x, 0.0f) * fw;
        acc[9] += fmaxf(e + d2.y, 0.0f) * fw;
        acc[10] += fmaxf(e + d2.z, 0.0f) * fw;
        acc[11] += fmaxf(e + d2.w, 0.0f) * fw;
    }
    float fb = fin_b[0];
    #pragma unroll
    for (int tt = 0; tt < 12; tt++)
        wts[((size_t)(tb + tt) * Bb + b) * Pp + p] = acc[tt] + fb;
}

__global__ void k_softmax(float* scores)
{
    int tb = blockIdx.x;
    float* row = scores + (size_t)tb * Pp;
    int lane = threadIdx.x; // 64
    float v[4];
    float mx = -1e30f;
    #pragma unroll
    for (int i = 0; i < 4; i++) {
        int p = lane + i * 64;
        v[i] = (p < Pp) ? row[p] : -1e30f;
        mx = fmaxf(mx, v[i]);
    }
    #pragma unroll
    for (int off = 32; off > 0; off >>= 1) mx = fmaxf(mx, __shfl_down(mx, off));
    mx = __shfl(mx, 0);
    float s = 0.0f;
    #pragma unroll
    for (int i = 0; i < 4; i++) {
        int p = lane + i * 64;
        v[i] = (p < Pp) ? expf(v[i] - mx) : 0.0f;
        s += v[i];
    }
    #pragma unroll
    for (int off = 32; off > 0; off >>= 1) s += __shfl_down(s, off);
    s = __shfl(s, 0);
    float inv = 1.0f / s;
    #pragma unroll
    for (int i = 0; i < 4; i++) {
        int p = lane + i * 64;
        if (p < Pp) row[p] = v[i] * inv;
    }
}

// ---------------- ctx_raw[t,b,:] = sum_p wts[t,b,p] * enc_s[b,p,:] ----------------
__global__ void k_ctx(const __bf16* __restrict__ enc, const float* __restrict__ wts,
                      float* __restrict__ ctx_raw)
{
    int b = blockIdx.y;
    int e = blockIdx.x * 256 + threadIdx.x;
    __shared__ float w_s[NSTEP][Pp];
    int tid = threadIdx.x;
    for (int idx = tid; idx < NSTEP * Pp; idx += 256) {
        int t = idx / Pp, p = idx % Pp;
        w_s[t][p] = wts[((size_t)t * Bb + b) * Pp + p];
    }
    __syncthreads();
    const __bf16* base = enc + (size_t)b * Pp * ENCc + e;
    float acc[NSTEP];
    #pragma unroll
    for (int t = 0; t < NSTEP; t++) acc[t] = 0.0f;
    for (int p = 0; p < Pp; p++) {
        float v = (float)base[(size_t)p * ENCc];
        #pragma unroll
        for (int t = 0; t < NSTEP; t++) acc[t] += w_s[t][p] * v;
    }
    for (int t = 0; t < NSTEP; t++)
        ctx_raw[((size_t)t * Bb + b) * ENCc + e] = acc[t];
}

// ---------------- fused recurrence: PERSISTENT-WEIGHT version ----------------
// NWG=128 workgroups x 256 threads. Each WG owns:
//   stage A: 16 consecutive xctx cols  (cb = wg*16), fbW rows cb..cb+15
//   stage B: 4 hidden cols (jb4 = wg*4), W2 rows {g*512 + jb4 + r : g<4, r<4}
//            (fragment col c  <->  W2 row (c>>2)*512 + jb4 + (c&3))
// The 4 waves split K: stage A 4 ksteps each (K=512), stage B 20 ksteps each
// (K=2560). All weight B-fragments are preloaded to VGPRs ONCE (96 VGPR) and
// live across all 24 timesteps -> no weight traffic, no LDS staging, and no
// __syncthreads inside the K-loops. Activations stream global->VGPR as MFMA
// A-fragments. Cross-wave K-reduction via 32KB LDS + one barrier, then the
// LSTM/gate epilogue (gates gathered with 4 shfls).
__launch_bounds__(256, 1)
__global__ void k_loop(__bf16* __restrict__ xctx, __bf16* __restrict__ hbuf0,
                       __bf16* __restrict__ hbuf1, float* __restrict__ cbuf,
                       const float* __restrict__ ctx_raw,
                       const __bf16* __restrict__ fbW, const float* __restrict__ fbb,
                       const __bf16* __restrict__ W2, const float* __restrict__ gdec,
                       __bf16* __restrict__ hall, const int* __restrict__ lens)
{
    cg::grid_group grid = cg::this_grid();
    __shared__ f32x4 red[4][8][64];    // [wave][Mfrag][lane] partials, 32 KB
    const int tid = threadIdx.x, lane = tid & 63, w = tid >> 6;
    const int wg = blockIdx.x;
    const int cl = lane & 15;          // row-within-16 of A frag / col of B frag
    const int koff = (lane >> 4) * 8;  // k-offset (elements) within K=32 granule
    const int rq4 = (lane >> 4) * 4;   // C-frag row quad
    const int cq = cl;                 // C-frag col
    const int jb4 = wg * 4;            // stage B hidden-col base
    const int cb = wg * 16;            // stage A xctx col base

    // ---- one-time weight preload into registers ----
    bf16x8 w2f[20];  // stage B B-frags: wave w owns ksteps w*20 .. w*20+19
    bf16x8 fbA[4];   // stage A B-frags: wave w owns ksteps w*4 .. w*4+3
    {
        const int Rrow = (cl >> 2) * 512 + jb4 + (cl & 3);
        #pragma unroll
        for (int jj = 0; jj < 20; jj++) {
            int ks = w * 20 + jj;
            w2f[jj] = *(const bf16x8*)(W2 + (size_t)Rrow * 2560 + ks * 32 + koff);
        }
        #pragma unroll
        for (int jj = 0; jj < 4; jj++) {
            int ks = w * 4 + jj;
            fbA[jj] = *(const bf16x8*)(fbW + (size_t)(cb + cl) * 512 + ks * 32 + koff);
        }
    }

    for (int t = 0; t < NSTEP; t++) {
        const __bf16* hcur = (t & 1) ? hbuf1 : hbuf0;
        __bf16* hnext = (t & 1) ? hbuf0 : hbuf1;

        // ---------- stage A: G = h @ fbW^T ; xctx = sigm(G+fbb)*ctx_raw ----------
        {
            f32x4 acc[8] = {};
            #pragma unroll
            for (int jj = 0; jj < 4; jj++) {
                const __bf16* Ab = hcur + (w * 4 + jj) * 32 + koff;
                bf16x8 a[8];
                #pragma unroll
                for (int m = 0; m < 8; m++)
                    a[m] = *(const bf16x8*)(Ab + (size_t)(m * 16 + cl) * 512);
                #pragma unroll
                for (int m = 0; m < 8; m++)
                    acc[m] = __builtin_amdgcn_mfma_f32_16x16x32_bf16(a[m], fbA[jj], acc[m], 0, 0, 0);
            }
            #pragma unroll
            for (int m = 0; m < 8; m++) red[w][m][lane] = acc[m];
            __syncthreads();
            // reduce across waves + epilogue: wave w owns M-frags 2w, 2w+1
            const float* cr = ctx_raw + (size_t)t * Bb * ENCc;
            #pragma unroll
            for (int mi = 0; mi < 2; mi++) {
                int m = w * 2 + mi;
                f32x4 s0 = red[0][m][lane], s1 = red[1][m][lane];
                f32x4 s2 = red[2][m][lane], s3 = red[3][m][lane];
                int col = cb + cq;
                float fb = fbb[col];
                #pragma unroll
                for (int r = 0; r < 4; r++) {
                    int row = m * 16 + rq4 + r;
                    float v = s0[r] + s1[r] + s2[r] + s3[r] + fb;
                    float x = sigm(v) * cr[(size_t)row * ENCc + col];
                    xctx[(size_t)row * ENCc + col] = (__bf16)x;
                }
            }
        }
        grid.sync();

        // ---------- stage B: gates = [xctx|h] @ W2^T (+gdec) ; LSTM ----------
        {
            f32x4 acc[8] = {};
            #pragma unroll
            for (int jj = 0; jj < 20; jj++) {
                const int ks = w * 20 + jj;        // global kstep 0..79
                const __bf16* Ab;
                int stride;
                if (ks < 64) { Ab = xctx + ks * 32 + koff; stride = ENCc; }
                else         { Ab = hcur + (ks - 64) * 32 + koff; stride = 512; }
                bf16x8 a[8];
                #pragma unroll
                for (int m = 0; m < 8; m++)
                    a[m] = *(const bf16x8*)(Ab + (size_t)(m * 16 + cl) * stride);
                #pragma unroll
                for (int m = 0; m < 8; m++)
                    acc[m] = __builtin_amdgcn_mfma_f32_16x16x32_bf16(a[m], w2f[jj], acc[m], 0, 0, 0);
            }
            #pragma unroll
            for (int m = 0; m < 8; m++) red[w][m][lane] = acc[m];
            __syncthreads();
            // reduce + LSTM epilogue
            const int gi = cq >> 2;        // which gate this frag col holds
            const int jo = cq & 3;         // hidden-col offset
            const int j = jb4 + jo;
            const int basel = lane & 48;
            const float* gd = gdec + (size_t)t * Bb * 2048;
            #pragma unroll
            for (int mi = 0; mi < 2; mi++) {
                int m = w * 2 + mi;
                f32x4 s0 = red[0][m][lane], s1 = red[1][m][lane];
                f32x4 s2 = red[2][m][lane], s3 = red[3][m][lane];
                #pragma unroll
                for (int r = 0; r < 4; r++) {
                    int row = m * 16 + rq4 + r;
                    float aval = s0[r] + s1[r] + s2[r] + s3[r]
                               + gd[(size_t)row * 2048 + gi * 512 + j];
                    // gather i,f,g,o for column j (all lanes participate)
                    float iv = __shfl(aval, basel | (0  + jo), 64);
                    float fv = __shfl(aval, basel | (4  + jo), 64);
                    float gv = __shfl(aval, basel | (8  + jo), 64);
                    float ov = __shfl(aval, basel | (12 + jo), 64);
                    float co = cbuf[(size_t)row * 512 + j];
                    float cn = sigm(fv) * co + sigm(iv) * tanhf(gv);
                    float hn = sigm(ov) * tanhf(cn);
                    bool act = lens[row] > (t + 1);
                    __bf16 hold = hcur[(size_t)row * 512 + j];
                    __bf16 hv = act ? (__bf16)hn : hold;
                    if (cq < 4) {
                        if (act) cbuf[(size_t)row * 512 + j] = cn;
                        hnext[(size_t)row * 512 + j] = hv;
                        hall[((size_t)t * Bb + row) * 512 + j] = hv;
                    }
                }
            }
        }
        grid.sync();
    }
}

extern "C" void kernel_launch(void* const* d_in, const int* in_sizes, int n_in,
                              void* d_out, int out_size, void* d_ws, size_t ws_size,
                              hipStream_t stream)
{
    const int*   captions    = (const int*)d_in[0];
    const float* encoder_out = (const float*)d_in[1];
    const int*   cap_lens    = (const int*)d_in[2];
    const float* emb_W       = (const float*)d_in[3];
    const float* att_enc_W   = (const float*)d_in[4];
    const float* att_enc_b   = (const float*)d_in[5];
    const float* att_dec_W   = (const float*)d_in[6];
    const float* att_dec_b   = (const float*)d_in[7];
    const float* att_fin_W   = (const float*)d_in[8];
    const float* att_fin_b   = (const float*)d_in[9];
    const float* f_beta_W    = (const float*)d_in[10];
    const float* f_beta_b    = (const float*)d_in[11];
    const float* W_ih        = (const float*)d_in[12];
    const float* b_ih        = (const float*)d_in[13];
    const float* W_hh        = (const float*)d_in[14];
    const float* b_hh        = (const float*)d_in[15];
    const float* lin_W       = (const float*)d_in[16];
    const float* lin_b       = (const float*)d_in[17];
    const float* h_init_W    = (const float*)d_in[18];
    const float* h_init_b    = (const float*)d_in[19];
    const float* c_init_W    = (const float*)d_in[20];
    const float* c_init_b    = (const float*)d_in[21];
    float* out = (float*)d_out;

    // ---- workspace carve ----
    float* f = (float*)d_ws;
    float* ctx_raw  = f; f += (size_t)NSTEP * Bb * ENCc;   // 6.29M
    float* att_d    = f; f += (size_t)NSTEP * Bb * Aa;     // 1.57M
    float* wts      = f; f += (size_t)NSTEP * Bb * Pp;     // 602k
    float* cbuf     = f; f += (size_t)Bb * Hh;
    float* gdec     = f; f += (size_t)NSTEP * Bb * 2048;   // 6.29M
    float* bias2    = f; f += 2048;
    float* bias_att = f; f += 512;
    __bf16* bp = (__bf16*)f;
    __bf16* enc_s = bp; bp += (size_t)Bb * Pp * ENCc + 131072;  // + guard pad
    __bf16* ET    = bp; bp += (size_t)Bb * Aa * Pp;             // 12.85M
    __bf16* attW  = bp; bp += (size_t)Aa * ENCc;
    __bf16* attdW = bp; bp += (size_t)Aa * Ee;
    __bf16* fbW   = bp; bp += (size_t)ENCc * Hh;
    __bf16* hiW   = bp; bp += (size_t)Hh * ENCc;
    __bf16* ciW   = bp; bp += (size_t)Hh * ENCc;
    __bf16* linWb = bp; bp += (size_t)NPAD * Hh;
    __bf16* embg  = bp; bp += (size_t)NSTEP * Bb * Ee;
    __bf16* hall  = bp; bp += (size_t)NSTEP * Bb * Hh;
    __bf16* hbuf0 = bp; bp += (size_t)Bb * Hh;
    __bf16* hbuf1 = bp; bp += (size_t)Bb * Hh;
    __bf16* emean = bp; bp += (size_t)Bb * ENCc;
    __bf16* W2    = bp; bp += (size_t)2048 * 2560;
    __bf16* Wihd  = bp; bp += (size_t)2048 * 512;
    __bf16* xctx  = bp; bp += (size_t)Bb * ENCc;
    int* ip = (int*)bp;
    int* sort_ind     = ip; ip += Bb;
    int* lens_s       = ip; ip += Bb;
    int* caps_s       = ip; ip += Bb * Tt;
    int* row_emb      = ip; ip += NSTEP * Bb;
    int* logit_rowoff = ip; ip += NSTEP * Bb;
    int* logit_mask   = ip; ip += NSTEP * Bb;

    // 1. sort + maps + int outputs ; preds[:,0] ; combined biases
    k_sort<<<1, Bb, 0, stream>>>(captions, cap_lens, sort_ind, lens_s, caps_s,
                                 row_emb, logit_rowoff, logit_mask, out);
    k_preds0<<<(Bb * Vv + 255) / 256, 256, 0, stream>>>(out);
    k_bias<<<8, 256, 0, stream>>>(b_ih, b_hh, att_enc_b, att_dec_b, bias2, bias_att);
    // 2. conversions
    k_cvt_enc<<<dim3(2, Bb * Pp), 256, 0, stream>>>(encoder_out, sort_ind, enc_s);
    k_cvt<<<(Aa * ENCc / 4 + 255) / 256, 256, 0, stream>>>(att_enc_W, attW, Aa * ENCc / 4);
    k_cvt<<<(Aa * Ee / 4 + 255) / 256, 256, 0, stream>>>(att_dec_W, attdW, Aa * Ee / 4);
    k_cvt<<<(ENCc * Hh / 4 + 255) / 256, 256, 0, stream>>>(f_beta_W, fbW, ENCc * Hh / 4);
    k_cvt<<<(Hh * ENCc / 4 + 255) / 256, 256, 0, stream>>>(h_init_W, hiW, Hh * ENCc / 4);
    k_cvt<<<(Hh * ENCc / 4 + 255) / 256, 256, 0, stream>>>(c_init_W, ciW, Hh * ENCc / 4);
    k_cvt_lin<<<(NPAD * 128 + 255) / 256, 256, 0, stream>>>(lin_W, linWb);
    k_cvt_emb<<<(NSTEP * Bb * 128) / 256, 256, 0, stream>>>(emb_W, row_emb, embg);
    k_cvt_wihd<<<(2048 * 128) / 256, 256, 0, stream>>>(W_ih, Wihd);
    k_wcat2<<<dim3(3, 2048), 256, 0, stream>>>(W_ih, W_hh, W2);
    // 3. enc mean ; h0 -> hbuf0 (bf16) ; c0 -> cbuf (f32)
    k_enc_mean<<<dim3(ENCc / 256, Bb), 256, 0, stream>>>(enc_s, emean);
    mfma_gemm<1><<<dim3(4, 1), 256, 0, stream>>>(emean, hiW, h_init_b, hbuf0,
        ENCc, Hh, 512, nullptr, nullptr, 0, 0, 0);
    mfma_gemm<0><<<dim3(4, 1), 256, 0, stream>>>(emean, ciW, c_init_b, cbuf,
        ENCc, Hh, 512, nullptr, nullptr, 0, 0, 0);
    // 4. ET[b] = attW @ enc_s[b]^T  (batched, M=512, N=196 padded 256, K=2048) -> bf16
    mfma_gemm<1><<<dim3(2, 4, Bb), 256, 0, stream>>>(attW, enc_s, nullptr, ET,
        ENCc, Pp, Pp, nullptr, nullptr, 0, (size_t)Pp * ENCc, (size_t)Aa * Pp);
    // 5. att_d (M=3072, N=512, K=512), combined bias
    mfma_gemm<0><<<dim3(4, NSTEP * Bb / 128), 256, 0, stream>>>(embg, attdW, bias_att, att_d,
        Ee, Aa, 512, nullptr, nullptr, 0, 0, 0);
    // 6. gdec = embg @ Wihd^T + bias2 (M=3072, N=2048, K=512)
    mfma_gemm<0><<<dim3(16, NSTEP * Bb / 128), 256, 0, stream>>>(embg, Wihd, bias2, gdec,
        Ee, 2048, 2048, nullptr, nullptr, 0, 0, 0);
    // 7. scores / softmax / ctx
    k_scores<<<dim3(2, Bb), 256, 0, stream>>>(ET, att_d, att_fin_W, att_fin_b, wts);
    k_softmax<<<NSTEP * Bb, 64, 0, stream>>>(wts);
    k_ctx<<<dim3(ENCc / 256, Bb), 256, 0, stream>>>(enc_s, wts, ctx_raw);
    // 8. fused recurrence (cooperative, persistent weights in VGPRs)
    {
        void* args[] = { &xctx, &hbuf0, &hbuf1, &cbuf, &ctx_raw, &fbW,
                         (void*)&f_beta_b, &W2, &gdec, &hall, &lens_s };
        hipLaunchCooperativeKernel((void*)k_loop, dim3(NWG), dim3(256), args, 0, stream);
    }
    // 9. logits (M=3072, N=10000 pad 10112, K=512), scatter+mask into preds
    mfma_gemm<2><<<dim3(NPAD / 128, NSTEP * Bb / 128), 256, 0, stream>>>(hall, linWb, lin_b, out,
        Hh, 0, Vv, logit_rowoff, logit_mask, 0, 0, 0);
}

// Round 2
// 2269.458 us; speedup vs baseline: 1.1845x; 1.1845x over previous
//
#include <hip/hip_runtime.h>
#include <hip/hip_cooperative_groups.h>
#include <math.h>

namespace cg = cooperative_groups;

#define Bb 128
#define Tt 25
#define Vv 10000
#define Ee 512
#define Aa 512
#define Hh 512
#define ENCc 2048
#define Pp 196
#define NSTEP 24
#define NPAD 10112  // 79*128
#define NWG 64      // cooperative loop workgroups

#define OUT_CAPS  ((size_t)Bb*Tt*Vv)            // 32,000,000
#define OUT_LENS  (OUT_CAPS + (size_t)Bb*Tt)    // 32,003,200
#define OUT_SORT  (OUT_LENS + Bb)               // 32,003,328

typedef __bf16 bf16x8 __attribute__((ext_vector_type(8)));
typedef __bf16 bf16x4 __attribute__((ext_vector_type(4)));
typedef float  f32x4  __attribute__((ext_vector_type(4)));

__device__ __forceinline__ float sigm(float x) { return 1.0f / (1.0f + expf(-x)); }

// ---- cheap grid barrier: one atomic + gen spin, agent scope ----
// bar[0] = arrival counter, bar[1] = generation
__device__ __forceinline__ void grid_barrier(int* bar)
{
    __syncthreads();
    if (threadIdx.x == 0) {
        __threadfence();   // release: make prior writes visible device-wide (L2 wb)
        int g = __hip_atomic_load(bar + 1, __ATOMIC_RELAXED, __HIP_MEMORY_SCOPE_AGENT);
        int a = __hip_atomic_fetch_add(bar, 1, __ATOMIC_ACQ_REL, __HIP_MEMORY_SCOPE_AGENT);
        if (a == NWG - 1) {
            __hip_atomic_store(bar, 0, __ATOMIC_RELAXED, __HIP_MEMORY_SCOPE_AGENT);
            __hip_atomic_store(bar + 1, g + 1, __ATOMIC_RELEASE, __HIP_MEMORY_SCOPE_AGENT);
        } else {
            while (__hip_atomic_load(bar + 1, __ATOMIC_ACQUIRE, __HIP_MEMORY_SCOPE_AGENT) == g)
                __builtin_amdgcn_s_sleep(2);
        }
        __threadfence();   // acquire: invalidate stale lines before re-reading
    }
    __syncthreads();
}

// ---------------- sort + index maps + int outputs ----------------
__global__ void k_sort(const int* __restrict__ captions, const int* __restrict__ cap_lens,
                       int* sort_ind, int* lens_s, int* caps_s,
                       int* row_emb, int* logit_rowoff, int* logit_mask,
                       float* out)
{
    int b = threadIdx.x; // 0..127
    __shared__ int lens_sh[Bb];
    int len = cap_lens[b];
    lens_sh[b] = len;
    __syncthreads();
    int r = 0;
    for (int k = 0; k < Bb; k++) {
        int lk = lens_sh[k];
        if (lk > len || (lk == len && k < b)) r++;
    }
    sort_ind[r] = b;
    lens_s[r] = len;
    for (int t = 0; t < Tt; t++) {
        int cv = captions[b * Tt + t];
        caps_s[r * Tt + t] = cv;
        out[OUT_CAPS + (size_t)r * Tt + t] = (float)cv;
    }
    out[OUT_LENS + r] = (float)len;
    out[OUT_SORT + r] = (float)b;
    __syncthreads();
    for (int m = b; m < NSTEP * Bb; m += Bb) {
        int t = m / Bb, bb = m % Bb;
        row_emb[m] = caps_s[bb * Tt + t];
        logit_rowoff[m] = (bb * Tt + (t + 1)) * Vv;
        logit_mask[m] = (lens_s[bb] > t + 1) ? 1 : 0;
    }
}

__global__ void k_preds0(float* out)
{
    size_t i = (size_t)blockIdx.x * 256 + threadIdx.x;
    if (i >= (size_t)Bb * Vv) return;
    size_t b = i / Vv, v = i % Vv;
    out[b * Tt * Vv + v] = (v == 0) ? 1.0f : 0.0f;
}

// bias2 = b_ih + b_hh ; bias_att = att_enc_b + att_dec_b ; zero grid barrier
__global__ void k_bias(const float* b_ih, const float* b_hh,
                       const float* aeb, const float* adb,
                       float* bias2, float* bias_att, int* bar)
{
    int i = blockIdx.x * 256 + threadIdx.x;
    if (i < 2048) bias2[i] = b_ih[i] + b_hh[i];
    if (i < 512)  bias_att[i] = aeb[i] + adb[i];
    if (i < 2)    bar[i] = 0;
}

// ---------------- conversions ----------------
__global__ void k_cvt_enc(const float* __restrict__ src, const int* __restrict__ sind,
                          __bf16* __restrict__ dst)
{
    int row = blockIdx.y;                       // sorted row
    int e4 = blockIdx.x * 256 + threadIdx.x;
    int b = row / Pp, p = row % Pp;
    const float4 v = *(const float4*)(src + ((size_t)(sind[b] * Pp + p)) * ENCc + e4 * 4);
    bf16x4 o = { (__bf16)v.x, (__bf16)v.y, (__bf16)v.z, (__bf16)v.w };
    *(bf16x4*)(dst + (size_t)row * ENCc + e4 * 4) = o;
}

__global__ void k_cvt(const float* __restrict__ src, __bf16* __restrict__ dst, int n4)
{
    int i = blockIdx.x * 256 + threadIdx.x;
    if (i >= n4) return;
    const float4 v = *(const float4*)(src + (size_t)i * 4);
    bf16x4 o = { (__bf16)v.x, (__bf16)v.y, (__bf16)v.z, (__bf16)v.w };
    *(bf16x4*)(dst + (size_t)i * 4) = o;
}

__global__ void k_cvt_lin(const float* __restrict__ src, __bf16* __restrict__ dst)
{
    int i = blockIdx.x * 256 + threadIdx.x;     // over NPAD*128
    if (i >= NPAD * 128) return;
    int row = i >> 7, e = (i & 127) * 4;
    bf16x4 o;
    if (row < Vv) {
        const float4 v = *(const float4*)(src + (size_t)row * Hh + e);
        o = bf16x4{ (__bf16)v.x, (__bf16)v.y, (__bf16)v.z, (__bf16)v.w };
    } else {
        o = bf16x4{ (__bf16)0.f, (__bf16)0.f, (__bf16)0.f, (__bf16)0.f };
    }
    *(bf16x4*)(dst + (size_t)row * Hh + e) = o;
}

__global__ void k_cvt_emb(const float* __restrict__ emb_W, const int* __restrict__ row_emb,
                          __bf16* __restrict__ dst)
{
    int i = blockIdx.x * 256 + threadIdx.x;     // over 3072*128
    int row = i >> 7, e = (i & 127) * 4;
    const float4 v = *(const float4*)(emb_W + (size_t)row_emb[row] * Ee + e);
    bf16x4 o = { (__bf16)v.x, (__bf16)v.y, (__bf16)v.z, (__bf16)v.w };
    *(bf16x4*)(dst + (size_t)row * Ee + e) = o;
}

// Wihd (2048x512 bf16) = W_ih[:, 2048:2560]
__global__ void k_cvt_wihd(const float* __restrict__ W_ih, __bf16* __restrict__ dst)
{
    int i = blockIdx.x * 256 + threadIdx.x;     // over 2048*128
    int row = i >> 7, e = (i & 127) * 4;
    const float4 v = *(const float4*)(W_ih + (size_t)row * 2560 + 2048 + e);
    bf16x4 o = { (__bf16)v.x, (__bf16)v.y, (__bf16)v.z, (__bf16)v.w };
    *(bf16x4*)(dst + (size_t)row * 512 + e) = o;
}

// W2 (2048x2560 bf16) = [W_ih[:, :2048] | W_hh]
__global__ void k_wcat2(const float* __restrict__ W_ih, const float* __restrict__ W_hh,
                        __bf16* __restrict__ W2)
{
    int n = blockIdx.y;
    int k4 = blockIdx.x * 256 + threadIdx.x;    // 0..639
    if (k4 >= 640) return;
    int k = k4 * 4;
    float4 v;
    if (k < 2048) v = *(const float4*)(W_ih + (size_t)n * 2560 + k);
    else          v = *(const float4*)(W_hh + (size_t)n * 512 + (k - 2048));
    bf16x4 o = { (__bf16)v.x, (__bf16)v.y, (__bf16)v.z, (__bf16)v.w };
    *(bf16x4*)(W2 + (size_t)n * 2560 + k) = o;
}

// ---------------- enc mean (bf16 in, bf16 out) ----------------
__global__ void k_enc_mean(const __bf16* __restrict__ enc, __bf16* __restrict__ emean)
{
    int b = blockIdx.y;
    int e = blockIdx.x * 256 + threadIdx.x;
    const __bf16* base = enc + (size_t)b * Pp * ENCc + e;
    float s = 0.0f;
    for (int p = 0; p < Pp; p++) s += (float)base[(size_t)p * ENCc];
    emean[(size_t)b * ENCc + e] = (__bf16)(s / 196.0f);
}

// ---------------- MFMA GEMM: C = A @ B^T (+bias), 128x128 tile, BK=32 ----------------
// MODE 0: f32 out row-major (stride Nout); MODE 1: bf16 out (stride Nout, col<Ncol)
// MODE 2: f32 out, row scatter (c_rowoff) + mask, col<Ncol
// batched via blockIdx.z with element strides bsA/bsB/bsC
template<int MODE>
__launch_bounds__(256)
__global__ void mfma_gemm(const __bf16* __restrict__ A, const __bf16* __restrict__ B,
                          const float* __restrict__ bias, void* __restrict__ Cout,
                          int K, int Nout, int Ncol,
                          const int* __restrict__ c_rowoff,
                          const int* __restrict__ mmask,
                          size_t bsA, size_t bsB, size_t bsC)
{
    __shared__ __bf16 sA[128 * 32];
    __shared__ __bf16 sB[128 * 32];
    const int tid = threadIdx.x;
    const int lane = tid & 63;
    const int wave = tid >> 6;
    const int z = blockIdx.z;
    const int m0 = blockIdx.y * 128, n0 = blockIdx.x * 128;
    const int wr = (wave & 1) * 64, wc = (wave >> 1) * 64;
    f32x4 acc[4][4] = {};
    const __bf16* Aptr = A + bsA * z + (size_t)m0 * K;
    const __bf16* Bptr = B + bsB * z + (size_t)n0 * K;
    const int c0 = tid, c1 = tid + 256;
    const int ar0 = c0 >> 2, ak0 = (c0 & 3) * 8;
    const int ar1 = c1 >> 2, ak1 = (c1 & 3) * 8;
    const int kq = (lane >> 4) * 8, mr = lane & 15;

    for (int k0 = 0; k0 < K; k0 += 32) {
        __builtin_amdgcn_global_load_lds(
            (const __attribute__((address_space(1))) void*)(Aptr + (size_t)ar0 * K + k0 + ak0),
            (__attribute__((address_space(3))) void*)(sA + c0 * 8), 16, 0, 0);
        __builtin_amdgcn_global_load_lds(
            (const __attribute__((address_space(1))) void*)(Aptr + (size_t)ar1 * K + k0 + ak1),
            (__attribute__((address_space(3))) void*)(sA + c1 * 8), 16, 0, 0);
        __builtin_amdgcn_global_load_lds(
            (const __attribute__((address_space(1))) void*)(Bptr + (size_t)ar0 * K + k0 + ak0),
            (__attribute__((address_space(3))) void*)(sB + c0 * 8), 16, 0, 0);
        __builtin_amdgcn_global_load_lds(
            (const __attribute__((address_space(1))) void*)(Bptr + (size_t)ar1 * K + k0 + ak1),
            (__attribute__((address_space(3))) void*)(sB + c1 * 8), 16, 0, 0);
        __syncthreads();
        bf16x8 af[4], bfr[4];
        #pragma unroll
        for (int i = 0; i < 4; i++)
            af[i] = *(const bf16x8*)(sA + (wr + i * 16 + mr) * 32 + kq);
        #pragma unroll
        for (int j = 0; j < 4; j++)
            bfr[j] = *(const bf16x8*)(sB + (wc + j * 16 + mr) * 32 + kq);
        #pragma unroll
        for (int i = 0; i < 4; i++)
            #pragma unroll
            for (int j = 0; j < 4; j++)
                acc[i][j] = __builtin_amdgcn_mfma_f32_16x16x32_bf16(af[i], bfr[j], acc[i][j], 0, 0, 0);
        __syncthreads();
    }

    const int rq = (lane >> 4) * 4, cq = lane & 15;
    #pragma unroll
    for (int i = 0; i < 4; i++) {
        #pragma unroll
        for (int j = 0; j < 4; j++) {
            #pragma unroll
            for (int r = 0; r < 4; r++) {
                int row = m0 + wr + i * 16 + rq + r;
                int col = n0 + wc + j * 16 + cq;
                if ((MODE == 1 || MODE == 2) && col >= Ncol) continue;
                float v = acc[i][j][r] + (bias ? bias[col] : 0.0f);
                size_t ro = (c_rowoff ? (size_t)c_rowoff[row] : (size_t)row * Nout) + bsC * z;
                if (MODE == 2) {
                    if (!mmask[row]) v = 0.0f;
                    ((float*)Cout)[ro + col] = v;
                } else if (MODE == 1) {
                    ((__bf16*)Cout)[ro + col] = (__bf16)v;
                } else {
                    ((float*)Cout)[ro + col] = v;
                }
            }
        }
    }
}

// ---------------- scores v3: reduction-free, lane<->p ----------------
// ET[b][a][196] bf16 (attenc^T, no bias), D = att_d[t*128+b][512] f32 (both biases folded)
__global__ void k_scores(const __bf16* __restrict__ ET, const float* __restrict__ att_d,
                         const float* __restrict__ fin_W, const float* __restrict__ fin_b,
                         float* __restrict__ wts)
{
    __shared__ float Dls[512 * 12];
    const int b = blockIdx.y;
    const int tb = blockIdx.x * 12;
    const int tid = threadIdx.x;
    #pragma unroll
    for (int tt = 0; tt < 12; tt++)
        for (int a = tid; a < 512; a += 256)
            Dls[a * 12 + tt] = att_d[((size_t)(tb + tt) * Bb + b) * Aa + a];
    __syncthreads();
    const int p = tid;
    if (p >= Pp) return;
    float acc[12];
    #pragma unroll
    for (int i = 0; i < 12; i++) acc[i] = 0.0f;
    const __bf16* ep = ET + (size_t)b * Aa * Pp + p;
    for (int a = 0; a < 512; a++) {
        float e = (float)ep[(size_t)a * Pp];
        float fw = fin_W[a];
        const float4* dp = (const float4*)(Dls + a * 12);
        float4 d0 = dp[0], d1 = dp[1], d2 = dp[2];
        acc[0] += fmaxf(e + d0.x, 0.0f) * fw;
        acc[1] += fmaxf(e + d0.y, 0.0f) * fw;
        acc[2] += fmaxf(e + d0.z, 0.0f) * fw;
        acc[3] += fmaxf(e + d0.w, 0.0f) * fw;
        acc[4] += fmaxf(e + d1.x, 0.0f) * fw;
        acc[5] += fmaxf(e + d1.y, 0.0f) * fw;
        acc[6] += fmaxf(e + d1.z, 0.0f) * fw;
        acc[7] += fmaxf(e + d1.w, 0.0f) * fw;
        acc[8] += fmaxf(e + d2.x, 0.0f) * fw;
        acc[9] += fmaxf(e + d2.y, 0.0f) * fw;
        acc[10] += fmaxf(e + d2.z, 0.0f) * fw;
        acc[11] += fmaxf(e + d2.w, 0.0f) * fw;
    }
    float fb = fin_b[0];
    #pragma unroll
    for (int tt = 0; tt < 12; tt++)
        wts[((size_t)(tb + tt) * Bb + b) * Pp + p] = acc[tt] + fb;
}

__global__ void k_softmax(float* scores)
{
    int tb = blockIdx.x;
    float* row = scores + (size_t)tb * Pp;
    int lane = threadIdx.x; // 64
    float v[4];
    float mx = -1e30f;
    #pragma unroll
    for (int i = 0; i < 4; i++) {
        int p = lane + i * 64;
        v[i] = (p < Pp) ? row[p] : -1e30f;
        mx = fmaxf(mx, v[i]);
    }
    #pragma unroll
    for (int off = 32; off > 0; off >>= 1) mx = fmaxf(mx, __shfl_down(mx, off));
    mx = __shfl(mx, 0);
    float s = 0.0f;
    #pragma unroll
    for (int i = 0; i < 4; i++) {
        int p = lane + i * 64;
        v[i] = (p < Pp) ? expf(v[i] - mx) : 0.0f;
        s += v[i];
    }
    #pragma unroll
    for (int off = 32; off > 0; off >>= 1) s += __shfl_down(s, off);
    s = __shfl(s, 0);
    float inv = 1.0f / s;
    #pragma unroll
    for (int i = 0; i < 4; i++) {
        int p = lane + i * 64;
        if (p < Pp) row[p] = v[i] * inv;
    }
}

// ---------------- ctx_raw[t,b,:] = sum_p wts[t,b,p] * enc_s[b,p,:] ----------------
__global__ void k_ctx(const __bf16* __restrict__ enc, const float* __restrict__ wts,
                      float* __restrict__ ctx_raw)
{
    int b = blockIdx.y;
    int e = blockIdx.x * 256 + threadIdx.x;
    __shared__ float w_s[NSTEP][Pp];
    int tid = threadIdx.x;
    for (int idx = tid; idx < NSTEP * Pp; idx += 256) {
        int t = idx / Pp, p = idx % Pp;
        w_s[t][p] = wts[((size_t)t * Bb + b) * Pp + p];
    }
    __syncthreads();
    const __bf16* base = enc + (size_t)b * Pp * ENCc + e;
    float acc[NSTEP];
    #pragma unroll
    for (int t = 0; t < NSTEP; t++) acc[t] = 0.0f;
    for (int p = 0; p < Pp; p++) {
        float v = (float)base[(size_t)p * ENCc];
        #pragma unroll
        for (int t = 0; t < NSTEP; t++) acc[t] += w_s[t][p] * v;
    }
    for (int t = 0; t < NSTEP; t++)
        ctx_raw[((size_t)t * Bb + b) * ENCc + e] = acc[t];
}

// ---------------- fused recurrence (cooperative, NWG=64 x 256) ----------------
// stage A: G = h @ fbW^T (128x2048,K=512); xctx = bf16(sigm(G+fbb)*ctx_raw[t])
// stage B: gates strips (4 gates x 8 cols per WG), K=2560 over [xctx|hcur]; LSTM epilogue
// grid syncs via hand-rolled agent-scope barrier (grid_barrier) - cg::sync measured ~20us.
__device__ __forceinline__ bf16x8 lds_frag(const __bf16* s, int row, int g)
{
    int slot = row * 16 + (g ^ (row & 7));
    return *(const bf16x8*)(s + slot * 8);
}

__launch_bounds__(256)
__global__ void k_loop(__bf16* __restrict__ xctx, __bf16* __restrict__ hbuf0,
                       __bf16* __restrict__ hbuf1, float* __restrict__ cbuf,
                       const float* __restrict__ ctx_raw,
                       const __bf16* __restrict__ fbW, const float* __restrict__ fbb,
                       const __bf16* __restrict__ W2, const float* __restrict__ gdec,
                       __bf16* __restrict__ hall, const int* __restrict__ lens,
                       int* __restrict__ bar)
{
    __shared__ __bf16 sA[128 * 128];   // 32 KB
    __shared__ __bf16 sB[32 * 128];    // 8 KB
    const int tid = threadIdx.x, lane = tid & 63, wave = tid >> 6;
    const int wg = blockIdx.x;
    const int cq = lane & 15, rq4 = (lane >> 4) * 4;
    const int mbase = wave * 32;
    const int kq = lane >> 4;          // k-granule sub-index

    for (int t = 0; t < NSTEP; t++) {
        const __bf16* hcur = (t & 1) ? hbuf1 : hbuf0;
        __bf16* hnext = (t & 1) ? hbuf0 : hbuf1;
        // ---------- stage A ----------
        {
            const int cb = wg * 32;
            f32x4 acc[2][2] = {};
            for (int k0 = 0; k0 < 512; k0 += 128) {
                #pragma unroll
                for (int i = 0; i < 8; i++) {
                    int flat = tid + 256 * i;
                    int row = flat >> 4, gs = flat & 15;
                    int gsrc = gs ^ (row & 7);
                    __builtin_amdgcn_global_load_lds(
                        (const __attribute__((address_space(1))) void*)(hcur + (size_t)row * 512 + k0 + gsrc * 8),
                        (__attribute__((address_space(3))) void*)(sA + flat * 8), 16, 0, 0);
                }
                #pragma unroll
                for (int i = 0; i < 2; i++) {
                    int flat = tid + 256 * i;
                    int row = flat >> 4, gs = flat & 15;
                    int gsrc = gs ^ (row & 7);
                    __builtin_amdgcn_global_load_lds(
                        (const __attribute__((address_space(1))) void*)(fbW + (size_t)(cb + row) * 512 + k0 + gsrc * 8),
                        (__attribute__((address_space(3))) void*)(sB + flat * 8), 16, 0, 0);
                }
                __syncthreads();
                #pragma unroll
                for (int ks = 0; ks < 4; ks++) {
                    int g = ks * 4 + kq;
                    bf16x8 af[2], bfv[2];
                    #pragma unroll
                    for (int mi = 0; mi < 2; mi++) af[mi] = lds_frag(sA, mbase + mi * 16 + cq, g);
                    #pragma unroll
                    for (int ni = 0; ni < 2; ni++) bfv[ni] = lds_frag(sB, ni * 16 + cq, g);
                    #pragma unroll
                    for (int mi = 0; mi < 2; mi++)
                        #pragma unroll
                        for (int ni = 0; ni < 2; ni++)
                            acc[mi][ni] = __builtin_amdgcn_mfma_f32_16x16x32_bf16(af[mi], bfv[ni], acc[mi][ni], 0, 0, 0);
                }
                __syncthreads();
            }
            const float* cr = ctx_raw + (size_t)t * Bb * ENCc;
            #pragma unroll
            for (int mi = 0; mi < 2; mi++)
                #pragma unroll
                for (int ni = 0; ni < 2; ni++)
                    #pragma unroll
                    for (int r = 0; r < 4; r++) {
                        int row = mbase + mi * 16 + rq4 + r;
                        int col = cb + ni * 16 + cq;
                        float v = acc[mi][ni][r] + fbb[col];
                        float x = sigm(v) * cr[(size_t)row * ENCc + col];
                        xctx[(size_t)row * ENCc + col] = (__bf16)x;
                    }
        }
        grid_barrier(bar);
        // ---------- stage B ----------
        {
            const int jb = wg * 8;
            f32x4 acc[2][2] = {};
            for (int k0 = 0; k0 < 2560; k0 += 128) {
                const bool inH = (k0 >= 2048);
                #pragma unroll
                for (int i = 0; i < 8; i++) {
                    int flat = tid + 256 * i;
                    int row = flat >> 4, gs = flat & 15;
                    int gsrc = gs ^ (row & 7);
                    const __bf16* src = inH ? (hcur + (size_t)row * 512 + (k0 - 2048) + gsrc * 8)
                                            : (xctx + (size_t)row * ENCc + k0 + gsrc * 8);
                    __builtin_amdgcn_global_load_lds(
                        (const __attribute__((address_space(1))) void*)src,
                        (__attribute__((address_space(3))) void*)(sA + flat * 8), 16, 0, 0);
                }
                #pragma unroll
                for (int i = 0; i < 2; i++) {
                    int flat = tid + 256 * i;
                    int row = flat >> 4, gs = flat & 15;
                    int gsrc = gs ^ (row & 7);
                    int wrow = (row >> 3) * 512 + jb + (row & 7);
                    __builtin_amdgcn_global_load_lds(
                        (const __attribute__((address_space(1))) void*)(W2 + (size_t)wrow * 2560 + k0 + gsrc * 8),
                        (__attribute__((address_space(3))) void*)(sB + flat * 8), 16, 0, 0);
                }
                __syncthreads();
                #pragma unroll
                for (int ks = 0; ks < 4; ks++) {
                    int g = ks * 4 + kq;
                    bf16x8 af[2], bfv[2];
                    #pragma unroll
                    for (int mi = 0; mi < 2; mi++) af[mi] = lds_frag(sA, mbase + mi * 16 + cq, g);
                    #pragma unroll
                    for (int ni = 0; ni < 2; ni++) bfv[ni] = lds_frag(sB, ni * 16 + cq, g);
                    #pragma unroll
                    for (int mi = 0; mi < 2; mi++)
                        #pragma unroll
                        for (int ni = 0; ni < 2; ni++)
                            acc[mi][ni] = __builtin_amdgcn_mfma_f32_16x16x32_bf16(af[mi], bfv[ni], acc[mi][ni], 0, 0, 0);
                }
                __syncthreads();
            }
            // LSTM epilogue: lane cq<8 holds (i,g); partner cq+8 holds (f,o)
            const int j = jb + (cq & 7);
            const int g0 = cq >> 3;
            #pragma unroll
            for (int mi = 0; mi < 2; mi++)
                #pragma unroll
                for (int r = 0; r < 4; r++) {
                    int row = mbase + mi * 16 + rq4 + r;
                    size_t gb = (size_t)(t * Bb + row) * 2048;
                    float a0 = acc[mi][0][r] + gdec[gb + (size_t)g0 * 512 + j];
                    float a1 = acc[mi][1][r] + gdec[gb + (size_t)(2 + g0) * 512 + j];
                    float p0 = __shfl_xor(a0, 8);
                    float p1 = __shfl_xor(a1, 8);
                    float iv, fv, gv, ov;
                    if (cq < 8) { iv = a0; gv = a1; fv = p0; ov = p1; }
                    else        { iv = p0; gv = p1; fv = a0; ov = a1; }
                    float co = cbuf[(size_t)row * 512 + j];
                    float cn = sigm(fv) * co + sigm(iv) * tanhf(gv);
                    float hn = sigm(ov) * tanhf(cn);
                    bool act = lens[row] > (t + 1);
                    __bf16 hold = hcur[(size_t)row * 512 + j];
                    __bf16 hv = act ? (__bf16)hn : hold;
                    if (cq < 8) {
                        if (act) cbuf[(size_t)row * 512 + j] = cn;
                        hnext[(size_t)row * 512 + j] = hv;
                        hall[((size_t)t * Bb + row) * 512 + j] = hv;
                    }
                }
        }
        grid_barrier(bar);
    }
}

extern "C" void kernel_launch(void* const* d_in, const int* in_sizes, int n_in,
                              void* d_out, int out_size, void* d_ws, size_t ws_size,
                              hipStream_t stream)
{
    const int*   captions    = (const int*)d_in[0];
    const float* encoder_out = (const float*)d_in[1];
    const int*   cap_lens    = (const int*)d_in[2];
    const float* emb_W       = (const float*)d_in[3];
    const float* att_enc_W   = (const float*)d_in[4];
    const float* att_enc_b   = (const float*)d_in[5];
    const float* att_dec_W   = (const float*)d_in[6];
    const float* att_dec_b   = (const float*)d_in[7];
    const float* att_fin_W   = (const float*)d_in[8];
    const float* att_fin_b   = (const float*)d_in[9];
    const float* f_beta_W    = (const float*)d_in[10];
    const float* f_beta_b    = (const float*)d_in[11];
    const float* W_ih        = (const float*)d_in[12];
    const float* b_ih        = (const float*)d_in[13];
    const float* W_hh        = (const float*)d_in[14];
    const float* b_hh        = (const float*)d_in[15];
    const float* lin_W       = (const float*)d_in[16];
    const float* lin_b       = (const float*)d_in[17];
    const float* h_init_W    = (const float*)d_in[18];
    const float* h_init_b    = (const float*)d_in[19];
    const float* c_init_W    = (const float*)d_in[20];
    const float* c_init_b    = (const float*)d_in[21];
    float* out = (float*)d_out;

    // ---- workspace carve ----
    float* f = (float*)d_ws;
    float* ctx_raw  = f; f += (size_t)NSTEP * Bb * ENCc;   // 6.29M
    float* att_d    = f; f += (size_t)NSTEP * Bb * Aa;     // 1.57M
    float* wts      = f; f += (size_t)NSTEP * Bb * Pp;     // 602k
    float* cbuf     = f; f += (size_t)Bb * Hh;
    float* gdec     = f; f += (size_t)NSTEP * Bb * 2048;   // 6.29M
    float* bias2    = f; f += 2048;
    float* bias_att = f; f += 512;
    __bf16* bp = (__bf16*)f;
    __bf16* enc_s = bp; bp += (size_t)Bb * Pp * ENCc + 131072;  // + guard pad
    __bf16* ET    = bp; bp += (size_t)Bb * Aa * Pp;             // 12.85M
    __bf16* attW  = bp; bp += (size_t)Aa * ENCc;
    __bf16* attdW = bp; bp += (size_t)Aa * Ee;
    __bf16* fbW   = bp; bp += (size_t)ENCc * Hh;
    __bf16* hiW   = bp; bp += (size_t)Hh * ENCc;
    __bf16* ciW   = bp; bp += (size_t)Hh * ENCc;
    __bf16* linWb = bp; bp += (size_t)NPAD * Hh;
    __bf16* embg  = bp; bp += (size_t)NSTEP * Bb * Ee;
    __bf16* hall  = bp; bp += (size_t)NSTEP * Bb * Hh;
    __bf16* hbuf0 = bp; bp += (size_t)Bb * Hh;
    __bf16* hbuf1 = bp; bp += (size_t)Bb * Hh;
    __bf16* emean = bp; bp += (size_t)Bb * ENCc;
    __bf16* W2    = bp; bp += (size_t)2048 * 2560;
    __bf16* Wihd  = bp; bp += (size_t)2048 * 512;
    __bf16* xctx  = bp; bp += (size_t)Bb * ENCc;
    int* ip = (int*)bp;
    int* sort_ind     = ip; ip += Bb;
    int* lens_s       = ip; ip += Bb;
    int* caps_s       = ip; ip += Bb * Tt;
    int* row_emb      = ip; ip += NSTEP * Bb;
    int* logit_rowoff = ip; ip += NSTEP * Bb;
    int* logit_mask   = ip; ip += NSTEP * Bb;
    ip = (int*)(((size_t)ip + 255) & ~(size_t)255);  // align barrier to its own line
    int* gbar         = ip; ip += 64;

    // 1. sort + maps + int outputs ; preds[:,0] ; combined biases ; barrier init
    k_sort<<<1, Bb, 0, stream>>>(captions, cap_lens, sort_ind, lens_s, caps_s,
                                 row_emb, logit_rowoff, logit_mask, out);
    k_preds0<<<(Bb * Vv + 255) / 256, 256, 0, stream>>>(out);
    k_bias<<<8, 256, 0, stream>>>(b_ih, b_hh, att_enc_b, att_dec_b, bias2, bias_att, gbar);
    // 2. conversions
    k_cvt_enc<<<dim3(2, Bb * Pp), 256, 0, stream>>>(encoder_out, sort_ind, enc_s);
    k_cvt<<<(Aa * ENCc / 4 + 255) / 256, 256, 0, stream>>>(att_enc_W, attW, Aa * ENCc / 4);
    k_cvt<<<(Aa * Ee / 4 + 255) / 256, 256, 0, stream>>>(att_dec_W, attdW, Aa * Ee / 4);
    k_cvt<<<(ENCc * Hh / 4 + 255) / 256, 256, 0, stream>>>(f_beta_W, fbW, ENCc * Hh / 4);
    k_cvt<<<(Hh * ENCc / 4 + 255) / 256, 256, 0, stream>>>(h_init_W, hiW, Hh * ENCc / 4);
    k_cvt<<<(Hh * ENCc / 4 + 255) / 256, 256, 0, stream>>>(c_init_W, ciW, Hh * ENCc / 4);
    k_cvt_lin<<<(NPAD * 128 + 255) / 256, 256, 0, stream>>>(lin_W, linWb);
    k_cvt_emb<<<(NSTEP * Bb * 128) / 256, 256, 0, stream>>>(emb_W, row_emb, embg);
    k_cvt_wihd<<<(2048 * 128) / 256, 256, 0, stream>>>(W_ih, Wihd);
    k_wcat2<<<dim3(3, 2048), 256, 0, stream>>>(W_ih, W_hh, W2);
    // 3. enc mean ; h0 -> hbuf0 (bf16) ; c0 -> cbuf (f32)
    k_enc_mean<<<dim3(ENCc / 256, Bb), 256, 0, stream>>>(enc_s, emean);
    mfma_gemm<1><<<dim3(4, 1), 256, 0, stream>>>(emean, hiW, h_init_b, hbuf0,
        ENCc, Hh, 512, nullptr, nullptr, 0, 0, 0);
    mfma_gemm<0><<<dim3(4, 1), 256, 0, stream>>>(emean, ciW, c_init_b, cbuf,
        ENCc, Hh, 512, nullptr, nullptr, 0, 0, 0);
    // 4. ET[b] = attW @ enc_s[b]^T  (batched, M=512, N=196 padded 256, K=2048) -> bf16
    mfma_gemm<1><<<dim3(2, 4, Bb), 256, 0, stream>>>(attW, enc_s, nullptr, ET,
        ENCc, Pp, Pp, nullptr, nullptr, 0, (size_t)Pp * ENCc, (size_t)Aa * Pp);
    // 5. att_d (M=3072, N=512, K=512), combined bias
    mfma_gemm<0><<<dim3(4, NSTEP * Bb / 128), 256, 0, stream>>>(embg, attdW, bias_att, att_d,
        Ee, Aa, 512, nullptr, nullptr, 0, 0, 0);
    // 6. gdec = embg @ Wihd^T + bias2 (M=3072, N=2048, K=512)
    mfma_gemm<0><<<dim3(16, NSTEP * Bb / 128), 256, 0, stream>>>(embg, Wihd, bias2, gdec,
        Ee, 2048, 2048, nullptr, nullptr, 0, 0, 0);
    // 7. scores / softmax / ctx
    k_scores<<<dim3(2, Bb), 256, 0, stream>>>(ET, att_d, att_fin_W, att_fin_b, wts);
    k_softmax<<<NSTEP * Bb, 64, 0, stream>>>(wts);
    k_ctx<<<dim3(ENCc / 256, Bb), 256, 0, stream>>>(enc_s, wts, ctx_raw);
    // 8. fused recurrence (cooperative, cheap custom grid barrier)
    {
        void* args[] = { &xctx, &hbuf0, &hbuf1, &cbuf, &ctx_raw, &fbW,
                         (void*)&f_beta_b, &W2, &gdec, &hall, &lens_s, &gbar };
        hipLaunchCooperativeKernel((void*)k_loop, dim3(NWG), dim3(256), args, 0, stream);
    }
    // 9. logits (M=3072, N=10000 pad 10112, K=512), scatter+mask into preds
    mfma_gemm<2><<<dim3(NPAD / 128, NSTEP * Bb / 128), 256, 0, stream>>>(hall, linWb, lin_b, out,
        Hh, 0, Vv, logit_rowoff, logit_mask, 0, 0, 0);
}

// Round 3
// 2110.606 us; speedup vs baseline: 1.2736x; 1.0753x over previous
//
#include <hip/hip_runtime.h>
#include <hip/hip_cooperative_groups.h>
#include <math.h>

namespace cg = cooperative_groups;

#define Bb 128
#define Tt 25
#define Vv 10000
#define Ee 512
#define Aa 512
#define Hh 512
#define ENCc 2048
#define Pp 196
#define NSTEP 24
#define NPAD 10112  // 79*128
#define NWG 64      // cooperative loop workgroups

#define OUT_CAPS  ((size_t)Bb*Tt*Vv)            // 32,000,000
#define OUT_LENS  (OUT_CAPS + (size_t)Bb*Tt)    // 32,003,200
#define OUT_SORT  (OUT_LENS + Bb)               // 32,003,328

typedef __bf16 bf16x8 __attribute__((ext_vector_type(8)));
typedef __bf16 bf16x4 __attribute__((ext_vector_type(4)));
typedef float  f32x4  __attribute__((ext_vector_type(4)));

__device__ __forceinline__ float sigm(float x) { return 1.0f / (1.0f + expf(-x)); }

// ---- cheap grid barrier: one atomic + gen spin, agent scope ----
// bar[0] = arrival counter, bar[1] = generation
__device__ __forceinline__ void grid_barrier(int* bar)
{
    __syncthreads();
    if (threadIdx.x == 0) {
        __threadfence();   // release: make prior writes visible device-wide (L2 wb)
        int g = __hip_atomic_load(bar + 1, __ATOMIC_RELAXED, __HIP_MEMORY_SCOPE_AGENT);
        int a = __hip_atomic_fetch_add(bar, 1, __ATOMIC_ACQ_REL, __HIP_MEMORY_SCOPE_AGENT);
        if (a == NWG - 1) {
            __hip_atomic_store(bar, 0, __ATOMIC_RELAXED, __HIP_MEMORY_SCOPE_AGENT);
            __hip_atomic_store(bar + 1, g + 1, __ATOMIC_RELEASE, __HIP_MEMORY_SCOPE_AGENT);
        } else {
            while (__hip_atomic_load(bar + 1, __ATOMIC_ACQUIRE, __HIP_MEMORY_SCOPE_AGENT) == g)
                __builtin_amdgcn_s_sleep(2);
        }
        __threadfence();   // acquire: invalidate stale lines before re-reading
    }
    __syncthreads();
}

// ---------------- sort + index maps + int outputs ----------------
__global__ void k_sort(const int* __restrict__ captions, const int* __restrict__ cap_lens,
                       int* sort_ind, int* lens_s, int* caps_s,
                       int* row_emb, int* logit_rowoff, int* logit_mask,
                       float* out)
{
    int b = threadIdx.x; // 0..127
    __shared__ int lens_sh[Bb];
    int len = cap_lens[b];
    lens_sh[b] = len;
    __syncthreads();
    int r = 0;
    for (int k = 0; k < Bb; k++) {
        int lk = lens_sh[k];
        if (lk > len || (lk == len && k < b)) r++;
    }
    sort_ind[r] = b;
    lens_s[r] = len;
    for (int t = 0; t < Tt; t++) {
        int cv = captions[b * Tt + t];
        caps_s[r * Tt + t] = cv;
        out[OUT_CAPS + (size_t)r * Tt + t] = (float)cv;
    }
    out[OUT_LENS + r] = (float)len;
    out[OUT_SORT + r] = (float)b;
    __syncthreads();
    for (int m = b; m < NSTEP * Bb; m += Bb) {
        int t = m / Bb, bb = m % Bb;
        row_emb[m] = caps_s[bb * Tt + t];
        logit_rowoff[m] = (bb * Tt + (t + 1)) * Vv;
        logit_mask[m] = (lens_s[bb] > t + 1) ? 1 : 0;
    }
}

__global__ void k_preds0(float* out)
{
    size_t i = (size_t)blockIdx.x * 256 + threadIdx.x;
    if (i >= (size_t)Bb * Vv) return;
    size_t b = i / Vv, v = i % Vv;
    out[b * Tt * Vv + v] = (v == 0) ? 1.0f : 0.0f;
}

// bias2 = b_ih + b_hh ; bias_att = att_enc_b + att_dec_b ; zero grid barrier
__global__ void k_bias(const float* b_ih, const float* b_hh,
                       const float* aeb, const float* adb,
                       float* bias2, float* bias_att, int* bar)
{
    int i = blockIdx.x * 256 + threadIdx.x;
    if (i < 2048) bias2[i] = b_ih[i] + b_hh[i];
    if (i < 512)  bias_att[i] = aeb[i] + adb[i];
    if (i < 2)    bar[i] = 0;
}

// ---------------- conversions ----------------
__global__ void k_cvt_enc(const float* __restrict__ src, const int* __restrict__ sind,
                          __bf16* __restrict__ dst)
{
    int row = blockIdx.y;                       // sorted row
    int e4 = blockIdx.x * 256 + threadIdx.x;
    int b = row / Pp, p = row % Pp;
    const float4 v = *(const float4*)(src + ((size_t)(sind[b] * Pp + p)) * ENCc + e4 * 4);
    bf16x4 o = { (__bf16)v.x, (__bf16)v.y, (__bf16)v.z, (__bf16)v.w };
    *(bf16x4*)(dst + (size_t)row * ENCc + e4 * 4) = o;
}

__global__ void k_cvt(const float* __restrict__ src, __bf16* __restrict__ dst, int n4)
{
    int i = blockIdx.x * 256 + threadIdx.x;
    if (i >= n4) return;
    const float4 v = *(const float4*)(src + (size_t)i * 4);
    bf16x4 o = { (__bf16)v.x, (__bf16)v.y, (__bf16)v.z, (__bf16)v.w };
    *(bf16x4*)(dst + (size_t)i * 4) = o;
}

__global__ void k_cvt_lin(const float* __restrict__ src, __bf16* __restrict__ dst)
{
    int i = blockIdx.x * 256 + threadIdx.x;     // over NPAD*128
    if (i >= NPAD * 128) return;
    int row = i >> 7, e = (i & 127) * 4;
    bf16x4 o;
    if (row < Vv) {
        const float4 v = *(const float4*)(src + (size_t)row * Hh + e);
        o = bf16x4{ (__bf16)v.x, (__bf16)v.y, (__bf16)v.z, (__bf16)v.w };
    } else {
        o = bf16x4{ (__bf16)0.f, (__bf16)0.f, (__bf16)0.f, (__bf16)0.f };
    }
    *(bf16x4*)(dst + (size_t)row * Hh + e) = o;
}

__global__ void k_cvt_emb(const float* __restrict__ emb_W, const int* __restrict__ row_emb,
                          __bf16* __restrict__ dst)
{
    int i = blockIdx.x * 256 + threadIdx.x;     // over 3072*128
    int row = i >> 7, e = (i & 127) * 4;
    const float4 v = *(const float4*)(emb_W + (size_t)row_emb[row] * Ee + e);
    bf16x4 o = { (__bf16)v.x, (__bf16)v.y, (__bf16)v.z, (__bf16)v.w };
    *(bf16x4*)(dst + (size_t)row * Ee + e) = o;
}

// Wihd (2048x512 bf16) = W_ih[:, 2048:2560]
__global__ void k_cvt_wihd(const float* __restrict__ W_ih, __bf16* __restrict__ dst)
{
    int i = blockIdx.x * 256 + threadIdx.x;     // over 2048*128
    int row = i >> 7, e = (i & 127) * 4;
    const float4 v = *(const float4*)(W_ih + (size_t)row * 2560 + 2048 + e);
    bf16x4 o = { (__bf16)v.x, (__bf16)v.y, (__bf16)v.z, (__bf16)v.w };
    *(bf16x4*)(dst + (size_t)row * 512 + e) = o;
}

// W2 (2048x2560 bf16) = [W_ih[:, :2048] | W_hh]
__global__ void k_wcat2(const float* __restrict__ W_ih, const float* __restrict__ W_hh,
                        __bf16* __restrict__ W2)
{
    int n = blockIdx.y;
    int k4 = blockIdx.x * 256 + threadIdx.x;    // 0..639
    if (k4 >= 640) return;
    int k = k4 * 4;
    float4 v;
    if (k < 2048) v = *(const float4*)(W_ih + (size_t)n * 2560 + k);
    else          v = *(const float4*)(W_hh + (size_t)n * 512 + (k - 2048));
    bf16x4 o = { (__bf16)v.x, (__bf16)v.y, (__bf16)v.z, (__bf16)v.w };
    *(bf16x4*)(W2 + (size_t)n * 2560 + k) = o;
}

// ---------------- enc mean (bf16 in, bf16 out) ----------------
__global__ void k_enc_mean(const __bf16* __restrict__ enc, __bf16* __restrict__ emean)
{
    int b = blockIdx.y;
    int e = blockIdx.x * 256 + threadIdx.x;
    const __bf16* base = enc + (size_t)b * Pp * ENCc + e;
    float s = 0.0f;
    for (int p = 0; p < Pp; p++) s += (float)base[(size_t)p * ENCc];
    emean[(size_t)b * ENCc + e] = (__bf16)(s / 196.0f);
}

// ---------------- MFMA GEMM: C = A @ B^T (+bias), 128x128 tile, BK=32 ----------------
// MODE 0: f32 out row-major (stride Nout); MODE 1: bf16 out (stride Nout, col<Ncol)
// MODE 2: f32 out, row scatter (c_rowoff) + mask, col<Ncol
// batched via blockIdx.z with element strides bsA/bsB/bsC
template<int MODE>
__launch_bounds__(256)
__global__ void mfma_gemm(const __bf16* __restrict__ A, const __bf16* __restrict__ B,
                          const float* __restrict__ bias, void* __restrict__ Cout,
                          int K, int Nout, int Ncol,
                          const int* __restrict__ c_rowoff,
                          const int* __restrict__ mmask,
                          size_t bsA, size_t bsB, size_t bsC)
{
    __shared__ __bf16 sA[128 * 32];
    __shared__ __bf16 sB[128 * 32];
    const int tid = threadIdx.x;
    const int lane = tid & 63;
    const int wave = tid >> 6;
    const int z = blockIdx.z;
    const int m0 = blockIdx.y * 128, n0 = blockIdx.x * 128;
    const int wr = (wave & 1) * 64, wc = (wave >> 1) * 64;
    f32x4 acc[4][4] = {};
    const __bf16* Aptr = A + bsA * z + (size_t)m0 * K;
    const __bf16* Bptr = B + bsB * z + (size_t)n0 * K;
    const int c0 = tid, c1 = tid + 256;
    const int ar0 = c0 >> 2, ak0 = (c0 & 3) * 8;
    const int ar1 = c1 >> 2, ak1 = (c1 & 3) * 8;
    const int kq = (lane >> 4) * 8, mr = lane & 15;

    for (int k0 = 0; k0 < K; k0 += 32) {
        __builtin_amdgcn_global_load_lds(
            (const __attribute__((address_space(1))) void*)(Aptr + (size_t)ar0 * K + k0 + ak0),
            (__attribute__((address_space(3))) void*)(sA + c0 * 8), 16, 0, 0);
        __builtin_amdgcn_global_load_lds(
            (const __attribute__((address_space(1))) void*)(Aptr + (size_t)ar1 * K + k0 + ak1),
            (__attribute__((address_space(3))) void*)(sA + c1 * 8), 16, 0, 0);
        __builtin_amdgcn_global_load_lds(
            (const __attribute__((address_space(1))) void*)(Bptr + (size_t)ar0 * K + k0 + ak0),
            (__attribute__((address_space(3))) void*)(sB + c0 * 8), 16, 0, 0);
        __builtin_amdgcn_global_load_lds(
            (const __attribute__((address_space(1))) void*)(Bptr + (size_t)ar1 * K + k0 + ak1),
            (__attribute__((address_space(3))) void*)(sB + c1 * 8), 16, 0, 0);
        __syncthreads();
        bf16x8 af[4], bfr[4];
        #pragma unroll
        for (int i = 0; i < 4; i++)
            af[i] = *(const bf16x8*)(sA + (wr + i * 16 + mr) * 32 + kq);
        #pragma unroll
        for (int j = 0; j < 4; j++)
            bfr[j] = *(const bf16x8*)(sB + (wc + j * 16 + mr) * 32 + kq);
        #pragma unroll
        for (int i = 0; i < 4; i++)
            #pragma unroll
            for (int j = 0; j < 4; j++)
                acc[i][j] = __builtin_amdgcn_mfma_f32_16x16x32_bf16(af[i], bfr[j], acc[i][j], 0, 0, 0);
        __syncthreads();
    }

    const int rq = (lane >> 4) * 4, cq = lane & 15;
    #pragma unroll
    for (int i = 0; i < 4; i++) {
        #pragma unroll
        for (int j = 0; j < 4; j++) {
            #pragma unroll
            for (int r = 0; r < 4; r++) {
                int row = m0 + wr + i * 16 + rq + r;
                int col = n0 + wc + j * 16 + cq;
                if ((MODE == 1 || MODE == 2) && col >= Ncol) continue;
                float v = acc[i][j][r] + (bias ? bias[col] : 0.0f);
                size_t ro = (c_rowoff ? (size_t)c_rowoff[row] : (size_t)row * Nout) + bsC * z;
                if (MODE == 2) {
                    if (!mmask[row]) v = 0.0f;
                    ((float*)Cout)[ro + col] = v;
                } else if (MODE == 1) {
                    ((__bf16*)Cout)[ro + col] = (__bf16)v;
                } else {
                    ((float*)Cout)[ro + col] = v;
                }
            }
        }
    }
}

// ---------------- scores v3: reduction-free, lane<->p ----------------
// ET[b][a][196] bf16 (attenc^T, no bias), D = att_d[t*128+b][512] f32 (both biases folded)
__global__ void k_scores(const __bf16* __restrict__ ET, const float* __restrict__ att_d,
                         const float* __restrict__ fin_W, const float* __restrict__ fin_b,
                         float* __restrict__ wts)
{
    __shared__ float Dls[512 * 12];
    const int b = blockIdx.y;
    const int tb = blockIdx.x * 12;
    const int tid = threadIdx.x;
    #pragma unroll
    for (int tt = 0; tt < 12; tt++)
        for (int a = tid; a < 512; a += 256)
            Dls[a * 12 + tt] = att_d[((size_t)(tb + tt) * Bb + b) * Aa + a];
    __syncthreads();
    const int p = tid;
    if (p >= Pp) return;
    float acc[12];
    #pragma unroll
    for (int i = 0; i < 12; i++) acc[i] = 0.0f;
    const __bf16* ep = ET + (size_t)b * Aa * Pp + p;
    for (int a = 0; a < 512; a++) {
        float e = (float)ep[(size_t)a * Pp];
        float fw = fin_W[a];
        const float4* dp = (const float4*)(Dls + a * 12);
        float4 d0 = dp[0], d1 = dp[1], d2 = dp[2];
        acc[0] += fmaxf(e + d0.x, 0.0f) * fw;
        acc[1] += fmaxf(e + d0.y, 0.0f) * fw;
        acc[2] += fmaxf(e + d0.z, 0.0f) * fw;
        acc[3] += fmaxf(e + d0.w, 0.0f) * fw;
        acc[4] += fmaxf(e + d1.x, 0.0f) * fw;
        acc[5] += fmaxf(e + d1.y, 0.0f) * fw;
        acc[6] += fmaxf(e + d1.z, 0.0f) * fw;
        acc[7] += fmaxf(e + d1.w, 0.0f) * fw;
        acc[8] += fmaxf(e + d2.x, 0.0f) * fw;
        acc[9] += fmaxf(e + d2.y, 0.0f) * fw;
        acc[10] += fmaxf(e + d2.z, 0.0f) * fw;
        acc[11] += fmaxf(e + d2.w, 0.0f) * fw;
    }
    float fb = fin_b[0];
    #pragma unroll
    for (int tt = 0; tt < 12; tt++)
        wts[((size_t)(tb + tt) * Bb + b) * Pp + p] = acc[tt] + fb;
}

__global__ void k_softmax(float* scores)
{
    int tb = blockIdx.x;
    float* row = scores + (size_t)tb * Pp;
    int lane = threadIdx.x; // 64
    float v[4];
    float mx = -1e30f;
    #pragma unroll
    for (int i = 0; i < 4; i++) {
        int p = lane + i * 64;
        v[i] = (p < Pp) ? row[p] : -1e30f;
        mx = fmaxf(mx, v[i]);
    }
    #pragma unroll
    for (int off = 32; off > 0; off >>= 1) mx = fmaxf(mx, __shfl_down(mx, off));
    mx = __shfl(mx, 0);
    float s = 0.0f;
    #pragma unroll
    for (int i = 0; i < 4; i++) {
        int p = lane + i * 64;
        v[i] = (p < Pp) ? expf(v[i] - mx) : 0.0f;
        s += v[i];
    }
    #pragma unroll
    for (int off = 32; off > 0; off >>= 1) s += __shfl_down(s, off);
    s = __shfl(s, 0);
    float inv = 1.0f / s;
    #pragma unroll
    for (int i = 0; i < 4; i++) {
        int p = lane + i * 64;
        if (p < Pp) row[p] = v[i] * inv;
    }
}

// ---------------- ctx_raw[t,b,:] = sum_p wts[t,b,p] * enc_s[b,p,:] ----------------
__global__ void k_ctx(const __bf16* __restrict__ enc, const float* __restrict__ wts,
                      float* __restrict__ ctx_raw)
{
    int b = blockIdx.y;
    int e = blockIdx.x * 256 + threadIdx.x;
    __shared__ float w_s[NSTEP][Pp];
    int tid = threadIdx.x;
    for (int idx = tid; idx < NSTEP * Pp; idx += 256) {
        int t = idx / Pp, p = idx % Pp;
        w_s[t][p] = wts[((size_t)t * Bb + b) * Pp + p];
    }
    __syncthreads();
    const __bf16* base = enc + (size_t)b * Pp * ENCc + e;
    float acc[NSTEP];
    #pragma unroll
    for (int t = 0; t < NSTEP; t++) acc[t] = 0.0f;
    for (int p = 0; p < Pp; p++) {
        float v = (float)base[(size_t)p * ENCc];
        #pragma unroll
        for (int t = 0; t < NSTEP; t++) acc[t] += w_s[t][p] * v;
    }
    for (int t = 0; t < NSTEP; t++)
        ctx_raw[((size_t)t * Bb + b) * ENCc + e] = acc[t];
}

// ---------------- fused recurrence (cooperative, NWG=64 x 256) ----------------
// Round-3: depth-2 software pipeline. 3-deep LDS buffers; batches stay in flight
// across raw s_barrier via counted s_waitcnt vmcnt(N) (never 0 until drain).
// Batch = 10 global_load_lds per thread per K-iter (8 sA + 2 sB), so steady
// wait is vmcnt(20) = 2 batches in flight. Epilogue operands (ctx_raw, gdec)
// prefetched to regs at stage top; c and h-hold live in registers across steps.
__device__ __forceinline__ bf16x8 lds_frag(const __bf16* s, int row, int g)
{
    int slot = row * 16 + (g ^ (row & 7));
    return *(const bf16x8*)(s + slot * 8);
}

__launch_bounds__(256)
__global__ void k_loop(__bf16* __restrict__ xctx, __bf16* __restrict__ hbuf0,
                       __bf16* __restrict__ hbuf1, float* __restrict__ cbuf,
                       const float* __restrict__ ctx_raw,
                       const __bf16* __restrict__ fbW, const float* __restrict__ fbb,
                       const __bf16* __restrict__ W2, const float* __restrict__ gdec,
                       __bf16* __restrict__ hall, const int* __restrict__ lens,
                       int* __restrict__ bar)
{
    __shared__ __bf16 sA[3][128 * 128];   // 96 KB, 3-deep
    __shared__ __bf16 sB[3][32 * 128];    // 24 KB, 3-deep
    const int tid = threadIdx.x, lane = tid & 63, wave = tid >> 6;
    const int wg = blockIdx.x;
    const int cq = lane & 15, rq4 = (lane >> 4) * 4;
    const int mbase = wave * 32;
    const int kq = lane >> 4;          // k-granule sub-index
    const int cb = wg * 32;            // stage A col base
    const int jb = wg * 8;             // stage B col base
    const int j = jb + (cq & 7);
    const int g0 = cq >> 3;

    // ---- loop-invariant / thread-owned state in registers ----
    float fbv[2];
    #pragma unroll
    for (int ni = 0; ni < 2; ni++) fbv[ni] = fbb[cb + ni * 16 + cq];
    int    lenv[2][4];
    float  creg[2][4];
    __bf16 hreg[2][4];
    #pragma unroll
    for (int mi = 0; mi < 2; mi++)
        #pragma unroll
        for (int r = 0; r < 4; r++) {
            int row = mbase + mi * 16 + rq4 + r;
            lenv[mi][r] = lens[row];
            creg[mi][r] = cbuf[(size_t)row * 512 + j];
            hreg[mi][r] = hbuf0[(size_t)row * 512 + j];
        }

    for (int t = 0; t < NSTEP; t++) {
        const __bf16* hcur = (t & 1) ? hbuf1 : hbuf0;
        __bf16* hnext = (t & 1) ? hbuf0 : hbuf1;

        // ---------- stage A: G = h @ fbW^T ; xctx = sigm(G+fbb)*ctx_raw ----------
        {
            const float* cr = ctx_raw + (size_t)t * Bb * ENCc;
            float crv[2][2][4];
            #pragma unroll
            for (int mi = 0; mi < 2; mi++)
                #pragma unroll
                for (int ni = 0; ni < 2; ni++)
                    #pragma unroll
                    for (int r = 0; r < 4; r++)
                        crv[mi][ni][r] = cr[(size_t)(mbase + mi * 16 + rq4 + r) * ENCc + cb + ni * 16 + cq];

            auto issueA = [&](int kk, int bi) {
                const int k0 = kk * 128;
                #pragma unroll
                for (int i = 0; i < 8; i++) {
                    int flat = tid + 256 * i;
                    int row = flat >> 4, gs = flat & 15, gsrc = gs ^ (row & 7);
                    __builtin_amdgcn_global_load_lds(
                        (const __attribute__((address_space(1))) void*)(hcur + (size_t)row * 512 + k0 + gsrc * 8),
                        (__attribute__((address_space(3))) void*)(&sA[bi][flat * 8]), 16, 0, 0);
                }
                #pragma unroll
                for (int i = 0; i < 2; i++) {
                    int flat = tid + 256 * i;
                    int row = flat >> 4, gs = flat & 15, gsrc = gs ^ (row & 7);
                    __builtin_amdgcn_global_load_lds(
                        (const __attribute__((address_space(1))) void*)(fbW + (size_t)(cb + row) * 512 + k0 + gsrc * 8),
                        (__attribute__((address_space(3))) void*)(&sB[bi][flat * 8]), 16, 0, 0);
                }
            };
            issueA(0, 0);
            issueA(1, 1);
            f32x4 acc[2][2] = {};
            for (int it = 0; it < 4; it++) {
                const int bi = it % 3;
                if (it + 2 < 4) issueA(it + 2, (it + 2) % 3);
                if (it < 2)       asm volatile("s_waitcnt vmcnt(20)" ::: "memory");
                else if (it == 2) asm volatile("s_waitcnt vmcnt(10)" ::: "memory");
                else              asm volatile("s_waitcnt vmcnt(0)" ::: "memory");
                __builtin_amdgcn_s_barrier();
                #pragma unroll
                for (int ks = 0; ks < 4; ks++) {
                    int g = ks * 4 + kq;
                    bf16x8 af[2], bfv[2];
                    #pragma unroll
                    for (int mi = 0; mi < 2; mi++) af[mi] = lds_frag(sA[bi], mbase + mi * 16 + cq, g);
                    #pragma unroll
                    for (int ni = 0; ni < 2; ni++) bfv[ni] = lds_frag(sB[bi], ni * 16 + cq, g);
                    #pragma unroll
                    for (int mi = 0; mi < 2; mi++)
                        #pragma unroll
                        for (int ni = 0; ni < 2; ni++)
                            acc[mi][ni] = __builtin_amdgcn_mfma_f32_16x16x32_bf16(af[mi], bfv[ni], acc[mi][ni], 0, 0, 0);
                }
                __builtin_amdgcn_s_barrier();
            }
            #pragma unroll
            for (int mi = 0; mi < 2; mi++)
                #pragma unroll
                for (int ni = 0; ni < 2; ni++)
                    #pragma unroll
                    for (int r = 0; r < 4; r++) {
                        int row = mbase + mi * 16 + rq4 + r;
                        int col = cb + ni * 16 + cq;
                        float v = acc[mi][ni][r] + fbv[ni];
                        float x = sigm(v) * crv[mi][ni][r];
                        xctx[(size_t)row * ENCc + col] = (__bf16)x;
                    }
        }
        grid_barrier(bar);

        // ---------- stage B: gates = [xctx|h] @ W2^T (+gdec) ; LSTM ----------
        {
            const float* gd = gdec + (size_t)t * Bb * 2048;
            float gdv[2][2][4];
            #pragma unroll
            for (int mi = 0; mi < 2; mi++)
                #pragma unroll
                for (int r = 0; r < 4; r++) {
                    int row = mbase + mi * 16 + rq4 + r;
                    gdv[mi][0][r] = gd[(size_t)row * 2048 + (size_t)g0 * 512 + j];
                    gdv[mi][1][r] = gd[(size_t)row * 2048 + (size_t)(2 + g0) * 512 + j];
                }
            auto issueB = [&](int kk, int bi) {
                const int k0 = kk * 128;
                const bool inH = (k0 >= 2048);
                #pragma unroll
                for (int i = 0; i < 8; i++) {
                    int flat = tid + 256 * i;
                    int row = flat >> 4, gs = flat & 15, gsrc = gs ^ (row & 7);
                    const __bf16* src = inH ? (hcur + (size_t)row * 512 + (k0 - 2048) + gsrc * 8)
                                            : (xctx + (size_t)row * ENCc + k0 + gsrc * 8);
                    __builtin_amdgcn_global_load_lds(
                        (const __attribute__((address_space(1))) void*)src,
                        (__attribute__((address_space(3))) void*)(&sA[bi][flat * 8]), 16, 0, 0);
                }
                #pragma unroll
                for (int i = 0; i < 2; i++) {
                    int flat = tid + 256 * i;
                    int row = flat >> 4, gs = flat & 15, gsrc = gs ^ (row & 7);
                    int wrow = (row >> 3) * 512 + jb + (row & 7);
                    __builtin_amdgcn_global_load_lds(
                        (const __attribute__((address_space(1))) void*)(W2 + (size_t)wrow * 2560 + k0 + gsrc * 8),
                        (__attribute__((address_space(3))) void*)(&sB[bi][flat * 8]), 16, 0, 0);
                }
            };
            issueB(0, 0);
            issueB(1, 1);
            f32x4 acc[2][2] = {};
            for (int it = 0; it < 20; it++) {
                const int bi = it % 3;
                if (it + 2 < 20) issueB(it + 2, (it + 2) % 3);
                if (it < 18)       asm volatile("s_waitcnt vmcnt(20)" ::: "memory");
                else if (it == 18) asm volatile("s_waitcnt vmcnt(10)" ::: "memory");
                else               asm volatile("s_waitcnt vmcnt(0)" ::: "memory");
                __builtin_amdgcn_s_barrier();
                #pragma unroll
                for (int ks = 0; ks < 4; ks++) {
                    int g = ks * 4 + kq;
                    bf16x8 af[2], bfv[2];
                    #pragma unroll
                    for (int mi = 0; mi < 2; mi++) af[mi] = lds_frag(sA[bi], mbase + mi * 16 + cq, g);
                    #pragma unroll
                    for (int ni = 0; ni < 2; ni++) bfv[ni] = lds_frag(sB[bi], ni * 16 + cq, g);
                    #pragma unroll
                    for (int mi = 0; mi < 2; mi++)
                        #pragma unroll
                        for (int ni = 0; ni < 2; ni++)
                            acc[mi][ni] = __builtin_amdgcn_mfma_f32_16x16x32_bf16(af[mi], bfv[ni], acc[mi][ni], 0, 0, 0);
                }
                __builtin_amdgcn_s_barrier();
            }
            // LSTM epilogue: lane cq<8 holds (i,g); partner cq+8 holds (f,o)
            #pragma unroll
            for (int mi = 0; mi < 2; mi++)
                #pragma unroll
                for (int r = 0; r < 4; r++) {
                    float a0 = acc[mi][0][r] + gdv[mi][0][r];
                    float a1 = acc[mi][1][r] + gdv[mi][1][r];
                    float p0 = __shfl_xor(a0, 8);
                    float p1 = __shfl_xor(a1, 8);
                    float iv, fv, gv, ov;
                    if (cq < 8) { iv = a0; gv = a1; fv = p0; ov = p1; }
                    else        { iv = p0; gv = p1; fv = a0; ov = a1; }
                    float cn = sigm(fv) * creg[mi][r] + sigm(iv) * tanhf(gv);
                    float hn = sigm(ov) * tanhf(cn);
                    bool act = lenv[mi][r] > (t + 1);
                    __bf16 hv = act ? (__bf16)hn : hreg[mi][r];
                    if (act) creg[mi][r] = cn;
                    hreg[mi][r] = hv;
                    if (cq < 8) {
                        int row = mbase + mi * 16 + rq4 + r;
                        hnext[(size_t)row * 512 + j] = hv;
                        hall[((size_t)t * Bb + row) * 512 + j] = hv;
                    }
                }
        }
        grid_barrier(bar);
    }
}

extern "C" void kernel_launch(void* const* d_in, const int* in_sizes, int n_in,
                              void* d_out, int out_size, void* d_ws, size_t ws_size,
                              hipStream_t stream)
{
    const int*   captions    = (const int*)d_in[0];
    const float* encoder_out = (const float*)d_in[1];
    const int*   cap_lens    = (const int*)d_in[2];
    const float* emb_W       = (const float*)d_in[3];
    const float* att_enc_W   = (const float*)d_in[4];
    const float* att_enc_b   = (const float*)d_in[5];
    const float* att_dec_W   = (const float*)d_in[6];
    const float* att_dec_b   = (const float*)d_in[7];
    const float* att_fin_W   = (const float*)d_in[8];
    const float* att_fin_b   = (const float*)d_in[9];
    const float* f_beta_W    = (const float*)d_in[10];
    const float* f_beta_b    = (const float*)d_in[11];
    const float* W_ih        = (const float*)d_in[12];
    const float* b_ih        = (const float*)d_in[13];
    const float* W_hh        = (const float*)d_in[14];
    const float* b_hh        = (const float*)d_in[15];
    const float* lin_W       = (const float*)d_in[16];
    const float* lin_b       = (const float*)d_in[17];
    const float* h_init_W    = (const float*)d_in[18];
    const float* h_init_b    = (const float*)d_in[19];
    const float* c_init_W    = (const float*)d_in[20];
    const float* c_init_b    = (const float*)d_in[21];
    float* out = (float*)d_out;

    // ---- workspace carve ----
    float* f = (float*)d_ws;
    float* ctx_raw  = f; f += (size_t)NSTEP * Bb * ENCc;   // 6.29M
    float* att_d    = f; f += (size_t)NSTEP * Bb * Aa;     // 1.57M
    float* wts      = f; f += (size_t)NSTEP * Bb * Pp;     // 602k
    float* cbuf     = f; f += (size_t)Bb * Hh;
    float* gdec     = f; f += (size_t)NSTEP * Bb * 2048;   // 6.29M
    float* bias2    = f; f += 2048;
    float* bias_att = f; f += 512;
    __bf16* bp = (__bf16*)f;
    __bf16* enc_s = bp; bp += (size_t)Bb * Pp * ENCc + 131072;  // + guard pad
    __bf16* ET    = bp; bp += (size_t)Bb * Aa * Pp;             // 12.85M
    __bf16* attW  = bp; bp += (size_t)Aa * ENCc;
    __bf16* attdW = bp; bp += (size_t)Aa * Ee;
    __bf16* fbW   = bp; bp += (size_t)ENCc * Hh;
    __bf16* hiW   = bp; bp += (size_t)Hh * ENCc;
    __bf16* ciW   = bp; bp += (size_t)Hh * ENCc;
    __bf16* linWb = bp; bp += (size_t)NPAD * Hh;
    __bf16* embg  = bp; bp += (size_t)NSTEP * Bb * Ee;
    __bf16* hall  = bp; bp += (size_t)NSTEP * Bb * Hh;
    __bf16* hbuf0 = bp; bp += (size_t)Bb * Hh;
    __bf16* hbuf1 = bp; bp += (size_t)Bb * Hh;
    __bf16* emean = bp; bp += (size_t)Bb * ENCc;
    __bf16* W2    = bp; bp += (size_t)2048 * 2560;
    __bf16* Wihd  = bp; bp += (size_t)2048 * 512;
    __bf16* xctx  = bp; bp += (size_t)Bb * ENCc;
    int* ip = (int*)bp;
    int* sort_ind     = ip; ip += Bb;
    int* lens_s       = ip; ip += Bb;
    int* caps_s       = ip; ip += Bb * Tt;
    int* row_emb      = ip; ip += NSTEP * Bb;
    int* logit_rowoff = ip; ip += NSTEP * Bb;
    int* logit_mask   = ip; ip += NSTEP * Bb;
    ip = (int*)(((size_t)ip + 255) & ~(size_t)255);  // align barrier to its own line
    int* gbar         = ip; ip += 64;

    // 1. sort + maps + int outputs ; preds[:,0] ; combined biases ; barrier init
    k_sort<<<1, Bb, 0, stream>>>(captions, cap_lens, sort_ind, lens_s, caps_s,
                                 row_emb, logit_rowoff, logit_mask, out);
    k_preds0<<<(Bb * Vv + 255) / 256, 256, 0, stream>>>(out);
    k_bias<<<8, 256, 0, stream>>>(b_ih, b_hh, att_enc_b, att_dec_b, bias2, bias_att, gbar);
    // 2. conversions
    k_cvt_enc<<<dim3(2, Bb * Pp), 256, 0, stream>>>(encoder_out, sort_ind, enc_s);
    k_cvt<<<(Aa * ENCc / 4 + 255) / 256, 256, 0, stream>>>(att_enc_W, attW, Aa * ENCc / 4);
    k_cvt<<<(Aa * Ee / 4 + 255) / 256, 256, 0, stream>>>(att_dec_W, attdW, Aa * Ee / 4);
    k_cvt<<<(ENCc * Hh / 4 + 255) / 256, 256, 0, stream>>>(f_beta_W, fbW, ENCc * Hh / 4);
    k_cvt<<<(Hh * ENCc / 4 + 255) / 256, 256, 0, stream>>>(h_init_W, hiW, Hh * ENCc / 4);
    k_cvt<<<(Hh * ENCc / 4 + 255) / 256, 256, 0, stream>>>(c_init_W, ciW, Hh * ENCc / 4);
    k_cvt_lin<<<(NPAD * 128 + 255) / 256, 256, 0, stream>>>(lin_W, linWb);
    k_cvt_emb<<<(NSTEP * Bb * 128) / 256, 256, 0, stream>>>(emb_W, row_emb, embg);
    k_cvt_wihd<<<(2048 * 128) / 256, 256, 0, stream>>>(W_ih, Wihd);
    k_wcat2<<<dim3(3, 2048), 256, 0, stream>>>(W_ih, W_hh, W2);
    // 3. enc mean ; h0 -> hbuf0 (bf16) ; c0 -> cbuf (f32)
    k_enc_mean<<<dim3(ENCc / 256, Bb), 256, 0, stream>>>(enc_s, emean);
    mfma_gemm<1><<<dim3(4, 1), 256, 0, stream>>>(emean, hiW, h_init_b, hbuf0,
        ENCc, Hh, 512, nullptr, nullptr, 0, 0, 0);
    mfma_gemm<0><<<dim3(4, 1), 256, 0, stream>>>(emean, ciW, c_init_b, cbuf,
        ENCc, Hh, 512, nullptr, nullptr, 0, 0, 0);
    // 4. ET[b] = attW @ enc_s[b]^T  (batched, M=512, N=196 padded 256, K=2048) -> bf16
    mfma_gemm<1><<<dim3(2, 4, Bb), 256, 0, stream>>>(attW, enc_s, nullptr, ET,
        ENCc, Pp, Pp, nullptr, nullptr, 0, (size_t)Pp * ENCc, (size_t)Aa * Pp);
    // 5. att_d (M=3072, N=512, K=512), combined bias
    mfma_gemm<0><<<dim3(4, NSTEP * Bb / 128), 256, 0, stream>>>(embg, attdW, bias_att, att_d,
        Ee, Aa, 512, nullptr, nullptr, 0, 0, 0);
    // 6. gdec = embg @ Wihd^T + bias2 (M=3072, N=2048, K=512)
    mfma_gemm<0><<<dim3(16, NSTEP * Bb / 128), 256, 0, stream>>>(embg, Wihd, bias2, gdec,
        Ee, 2048, 2048, nullptr, nullptr, 0, 0, 0);
    // 7. scores / softmax / ctx
    k_scores<<<dim3(2, Bb), 256, 0, stream>>>(ET, att_d, att_fin_W, att_fin_b, wts);
    k_softmax<<<NSTEP * Bb, 64, 0, stream>>>(wts);
    k_ctx<<<dim3(ENCc / 256, Bb), 256, 0, stream>>>(enc_s, wts, ctx_raw);
    // 8. fused recurrence (cooperative, depth-2 pipelined K-loops)
    {
        void* args[] = { &xctx, &hbuf0, &hbuf1, &cbuf, &ctx_raw, &fbW,
                         (void*)&f_beta_b, &W2, &gdec, &hall, &lens_s, &gbar };
        hipLaunchCooperativeKernel((void*)k_loop, dim3(NWG), dim3(256), args, 0, stream);
    }
    // 9. logits (M=3072, N=10000 pad 10112, K=512), scatter+mask into preds
    mfma_gemm<2><<<dim3(NPAD / 128, NSTEP * Bb / 128), 256, 0, stream>>>(hall, linWb, lin_b, out,
        Hh, 0, Vv, logit_rowoff, logit_mask, 0, 0, 0);
}